// Round 1
// baseline (752.074 us; speedup 1.0000x reference)
//
#include <hip/hip_runtime.h>
#include <math.h>

#define NB 8
#define NC 512
#define NN 1024      // H*W
#define NHEADS 8
#define NDIM 64
#define OQKV 1536
#define EPSV 1e-5f

// ws layout (floats):
#define WS_PART_SUM 0            // 512
#define WS_PART_SQ  1024         // 512
#define WS_MU       2048         // 8
#define WS_RSTD     2056         // 8
#define WS_XN       4096         // NB*NC*NN = 4194304  (later reused as VALS)
#define WS_QKV      (4096 + 4194304)   // NB*OQKV*NN = 12582912

// ---------------- stage 1: partial sum/sumsq per batch ----------------
__global__ __launch_bounds__(256) void reduce_partial(const float* __restrict__ x,
                                                      float* __restrict__ ws) {
    int b = blockIdx.x >> 6;   // 64 blocks per batch
    int s = blockIdx.x & 63;
    const float* xb = x + (size_t)b * (NC * NN) + (size_t)s * 8192;
    float sum = 0.f, sq = 0.f;
    for (int i = threadIdx.x; i < 2048; i += 256) {
        float4 v = ((const float4*)xb)[i];
        sum += v.x + v.y + v.z + v.w;
        sq  += v.x*v.x + v.y*v.y + v.z*v.z + v.w*v.w;
    }
    #pragma unroll
    for (int off = 32; off; off >>= 1) {
        sum += __shfl_down(sum, off);
        sq  += __shfl_down(sq,  off);
    }
    __shared__ float s1[4], s2[4];
    int wave = threadIdx.x >> 6, lane = threadIdx.x & 63;
    if (lane == 0) { s1[wave] = sum; s2[wave] = sq; }
    __syncthreads();
    if (threadIdx.x == 0) {
        float a = 0.f, c2 = 0.f;
        #pragma unroll
        for (int w = 0; w < 4; w++) { a += s1[w]; c2 += s2[w]; }
        ws[WS_PART_SUM + b*64 + s] = a;
        ws[WS_PART_SQ  + b*64 + s] = c2;
    }
}

// ---------------- stage 2: finalize mu / rstd ----------------
__global__ void finalize_stats(float* __restrict__ ws) {
    int b = threadIdx.x;
    if (b < NB) {
        float s = 0.f, q = 0.f;
        for (int i = 0; i < 64; i++) {
            s += ws[WS_PART_SUM + b*64 + i];
            q += ws[WS_PART_SQ  + b*64 + i];
        }
        const float inv = 1.f / (float)(NC * NN);
        float mu  = s * inv;
        float var = q * inv - mu * mu;
        ws[WS_MU + b]   = mu;
        ws[WS_RSTD + b] = rsqrtf(var + EPSV);
    }
}

// ---------------- normalize: xn = (x-mu)*rstd*gamma + beta ----------------
__global__ __launch_bounds__(256) void normalize_kernel(const float* __restrict__ x,
                                                        const float* __restrict__ gamma,
                                                        const float* __restrict__ beta,
                                                        const float* __restrict__ ws,
                                                        float* __restrict__ xn) {
    size_t i = ((size_t)blockIdx.x * 256 + threadIdx.x) * 4;
    int b = (int)(i >> 19);          // / (NC*NN) = 2^19
    int c = (int)((i >> 10) & 511);  // / NN % NC
    float mu = ws[WS_MU + b], rstd = ws[WS_RSTD + b];
    float g  = gamma[c] * rstd;
    float be = beta[c] - mu * rstd * gamma[c];
    float4 v = *(const float4*)(x + i);
    float4 o;
    o.x = v.x*g + be; o.y = v.y*g + be; o.z = v.z*g + be; o.w = v.w*g + be;
    *(float4*)(xn + i) = o;
}

// ---------------- tiled fp32 GEMM: Y[b,o,n] = sum_c X[b,c,n]*W[o,c] + bias[o] ----------------
template<int O>
__global__ __launch_bounds__(256) void gemm_xw(const float* __restrict__ X,
                                               const float* __restrict__ W,
                                               const float* __restrict__ bias,
                                               float* __restrict__ Y,
                                               int Cd) {
    const int NT = NN / 64;
    const int OT = O / 64;
    int nt = blockIdx.x % NT;
    int ot = (blockIdx.x / NT) % OT;
    int b  = blockIdx.x / (NT * OT);
    const float* Xb = X + (size_t)b * Cd * NN;
    __shared__ float lw[16][64];
    __shared__ float lx[16][64];
    const int t = threadIdx.x;
    const int tx = t & 15, ty = t >> 4;
    float acc[4][4] = {};
    const int o0 = ot * 64, n0 = nt * 64;
    for (int c0 = 0; c0 < Cd; c0 += 16) {
        int oo = t >> 2, k4 = (t & 3) * 4;
        float4 wv = *(const float4*)(W + (size_t)(o0 + oo) * Cd + c0 + k4);
        int kk = t >> 4, n4 = (t & 15) * 4;
        float4 xv = *(const float4*)(Xb + (size_t)(c0 + kk) * NN + n0 + n4);
        __syncthreads();   // prior compute done before overwriting LDS
        lw[k4+0][oo] = wv.x; lw[k4+1][oo] = wv.y; lw[k4+2][oo] = wv.z; lw[k4+3][oo] = wv.w;
        *(float4*)&lx[kk][n4] = xv;
        __syncthreads();
        #pragma unroll
        for (int k2 = 0; k2 < 16; k2++) {
            float4 a  = *(const float4*)&lw[k2][ty*4];
            float4 bx = *(const float4*)&lx[k2][tx*4];
            acc[0][0]+=a.x*bx.x; acc[0][1]+=a.x*bx.y; acc[0][2]+=a.x*bx.z; acc[0][3]+=a.x*bx.w;
            acc[1][0]+=a.y*bx.x; acc[1][1]+=a.y*bx.y; acc[1][2]+=a.y*bx.z; acc[1][3]+=a.y*bx.w;
            acc[2][0]+=a.z*bx.x; acc[2][1]+=a.z*bx.y; acc[2][2]+=a.z*bx.z; acc[2][3]+=a.z*bx.w;
            acc[3][0]+=a.w*bx.x; acc[3][1]+=a.w*bx.y; acc[3][2]+=a.w*bx.z; acc[3][3]+=a.w*bx.w;
        }
    }
    #pragma unroll
    for (int i = 0; i < 4; i++) {
        float bi = bias[o0 + ty*4 + i];
        float4 r;
        r.x = acc[i][0] + bi; r.y = acc[i][1] + bi; r.z = acc[i][2] + bi; r.w = acc[i][3] + bi;
        *(float4*)(Y + ((size_t)b * O + o0 + ty*4 + i) * NN + n0 + tx*4) = r;
    }
}

// ---------------- flash attention: per (b, h, 32-query tile) ----------------
__global__ __launch_bounds__(256) void attn_kernel(const float* __restrict__ qkv,
                                                   float* __restrict__ vals) {
    const int qt = blockIdx.x & 31;
    const int h  = (blockIdx.x >> 5) & 7;
    const int b  = blockIdx.x >> 8;
    const float scale = 0.04419417382415922f;   // 512^-0.5
    const float* Q = qkv + ((size_t)b * OQKV + h * NDIM) * NN;
    const float* K = Q + (size_t)512 * NN;
    const float* V = Q + (size_t)1024 * NN;

    __shared__ float q_s[64][33];
    __shared__ float k_s[64][36];
    __shared__ float v_s[64][36];
    __shared__ float p_s[32][36];

    const int t   = threadIdx.x;
    const int qi  = t >> 3;     // 0..31 query within tile
    const int sub = t & 7;      // 0..7
    const int n0  = qt * 32;

    // stage Q tile (64 d x 32 q)
    #pragma unroll
    for (int r = 0; r < 2; r++) {
        int idx4 = t * 2 + r;            // 0..511 float4s
        int d  = idx4 >> 3;
        int c4 = (idx4 & 7) * 4;
        float4 v = *(const float4*)(Q + (size_t)d * NN + n0 + c4);
        q_s[d][c4+0] = v.x; q_s[d][c4+1] = v.y; q_s[d][c4+2] = v.z; q_s[d][c4+3] = v.w;
    }
    __syncthreads();
    float qreg[64];
    #pragma unroll
    for (int d = 0; d < 64; d++) qreg[d] = q_s[d][qi];

    float m_run = -INFINITY, l_run = 0.f;
    float acc[8] = {};

    for (int ck = 0; ck < 32; ck++) {
        const int m0 = ck * 32;
        __syncthreads();   // prior PV reads complete before overwriting K/V
        #pragma unroll
        for (int r = 0; r < 2; r++) {
            int idx4 = t * 2 + r;
            int d  = idx4 >> 3;
            int c4 = (idx4 & 7) * 4;
            float4 kv = *(const float4*)(K + (size_t)d * NN + m0 + c4);
            float4 vv = *(const float4*)(V + (size_t)d * NN + m0 + c4);
            *(float4*)&k_s[d][c4] = kv;
            *(float4*)&v_s[d][c4] = vv;
        }
        __syncthreads();

        // scores: row qi, cols sub*4..sub*4+3
        float sc[4] = {0.f, 0.f, 0.f, 0.f};
        #pragma unroll
        for (int d = 0; d < 64; d++) {
            float4 k4v = *(const float4*)&k_s[d][sub*4];
            float qv = qreg[d];
            sc[0] += qv * k4v.x; sc[1] += qv * k4v.y; sc[2] += qv * k4v.z; sc[3] += qv * k4v.w;
        }
        #pragma unroll
        for (int j = 0; j < 4; j++) sc[j] *= scale;

        // online softmax within the 8-lane row group
        float cmax = fmaxf(fmaxf(sc[0], sc[1]), fmaxf(sc[2], sc[3]));
        cmax = fmaxf(cmax, __shfl_xor(cmax, 1));
        cmax = fmaxf(cmax, __shfl_xor(cmax, 2));
        cmax = fmaxf(cmax, __shfl_xor(cmax, 4));
        float m_new = fmaxf(m_run, cmax);
        float resc  = __expf(m_run - m_new);
        float p[4], ls = 0.f;
        #pragma unroll
        for (int j = 0; j < 4; j++) { p[j] = __expf(sc[j] - m_new); ls += p[j]; }
        ls += __shfl_xor(ls, 1); ls += __shfl_xor(ls, 2); ls += __shfl_xor(ls, 4);
        l_run = l_run * resc + ls;
        m_run = m_new;
        *(float4*)&p_s[qi][sub*4] = make_float4(p[0], p[1], p[2], p[3]);
        #pragma unroll
        for (int j = 0; j < 8; j++) acc[j] *= resc;
        __syncthreads();

        // PV: acc[j] += sum_m p[qi][m] * v[sub+8j][m]
        float4 p4[8];
        #pragma unroll
        for (int m4 = 0; m4 < 8; m4++) p4[m4] = *(const float4*)&p_s[qi][m4*4];
        #pragma unroll
        for (int j = 0; j < 8; j++) {
            const int d = sub + 8*j;
            float a = acc[j];
            #pragma unroll
            for (int m4 = 0; m4 < 8; m4++) {
                float4 v4 = *(const float4*)&v_s[d][m4*4];
                a += p4[m4].x*v4.x + p4[m4].y*v4.y + p4[m4].z*v4.z + p4[m4].w*v4.w;
            }
            acc[j] = a;
        }
    }

    float inv_l = 1.f / l_run;
    #pragma unroll
    for (int j = 0; j < 8; j++) {
        int d = sub + 8*j;
        vals[((size_t)b * NC + h * NDIM + d) * NN + n0 + qi] = acc[j] * inv_l;
    }
}

extern "C" void kernel_launch(void* const* d_in, const int* in_sizes, int n_in,
                              void* d_out, int out_size, void* d_ws, size_t ws_size,
                              hipStream_t stream) {
    const float* x      = (const float*)d_in[0];
    const float* gamma  = (const float*)d_in[1];
    const float* beta   = (const float*)d_in[2];
    const float* w_qkv  = (const float*)d_in[3];
    const float* b_qkv  = (const float*)d_in[4];
    const float* w_proj = (const float*)d_in[5];
    const float* b_proj = (const float*)d_in[6];
    float* ws   = (float*)d_ws;
    float* out  = (float*)d_out;
    float* xn   = ws + WS_XN;
    float* qkv  = ws + WS_QKV;
    float* vals = ws + WS_XN;   // reuse xn region after QKV GEMM consumes it

    hipLaunchKernelGGL(reduce_partial, dim3(NB * 64), dim3(256), 0, stream, x, ws);
    hipLaunchKernelGGL(finalize_stats, dim3(1), dim3(64), 0, stream, ws);
    hipLaunchKernelGGL(normalize_kernel, dim3(4096), dim3(256), 0, stream, x, gamma, beta, ws, xn);
    hipLaunchKernelGGL(gemm_xw<OQKV>, dim3(NB * (OQKV/64) * (NN/64)), dim3(256), 0, stream,
                       xn, w_qkv, b_qkv, qkv, NC);
    hipLaunchKernelGGL(attn_kernel, dim3(NB * NHEADS * 32), dim3(256), 0, stream, qkv, vals);
    hipLaunchKernelGGL(gemm_xw<NC>, dim3(NB * (NC/64) * (NN/64)), dim3(256), 0, stream,
                       vals, w_proj, b_proj, out, NC);
}

// Round 2
// 294.781 us; speedup vs baseline: 2.5513x; 2.5513x over previous
//
#include <hip/hip_runtime.h>
#include <hip/hip_bf16.h>
#include <math.h>

#define NB 8
#define NC 512
#define NN 1024      // H*W
#define NHEADS 8
#define NDIM 64
#define OQKV 1536
#define EPSV 1e-5f

typedef __attribute__((ext_vector_type(8))) short bf16x8;
typedef __attribute__((ext_vector_type(4))) short bf16x4;
typedef __attribute__((ext_vector_type(4))) float f32x4;

#define MFMA16(a,b,c) __builtin_amdgcn_mfma_f32_16x16x32_bf16(a,b,c,0,0,0)

static __device__ __forceinline__ short f2bf(float f) {
    __hip_bfloat16 h = __float2bfloat16(f);
    return *reinterpret_cast<short*>(&h);
}

// ws layout (float offsets):
#define WS_PART_SUM 0            // 512
#define WS_PART_SQ  1024         // 512
#define WS_MU       2048         // 8
#define WS_RSTD     2056         // 8
#define WS_XN       4096                       // 4,194,304 f32 (xn; reused as vals)
#define WS_QT       (4096 + 4194304)           // 2,097,152 f32-equiv (4.19M bf16)
#define WS_KT       (WS_QT + 2097152)
#define WS_V        (WS_KT + 2097152)
// end = 10,489,856 floats = 42 MB

// ---------------- stage 1: partial sum/sumsq per batch ----------------
__global__ __launch_bounds__(256) void reduce_partial(const float* __restrict__ x,
                                                      float* __restrict__ ws) {
    int b = blockIdx.x >> 6;
    int s = blockIdx.x & 63;
    const float* xb = x + (size_t)b * (NC * NN) + (size_t)s * 8192;
    float sum = 0.f, sq = 0.f;
    for (int i = threadIdx.x; i < 2048; i += 256) {
        float4 v = ((const float4*)xb)[i];
        sum += v.x + v.y + v.z + v.w;
        sq  += v.x*v.x + v.y*v.y + v.z*v.z + v.w*v.w;
    }
    #pragma unroll
    for (int off = 32; off; off >>= 1) {
        sum += __shfl_down(sum, off);
        sq  += __shfl_down(sq,  off);
    }
    __shared__ float s1[4], s2[4];
    int wave = threadIdx.x >> 6, lane = threadIdx.x & 63;
    if (lane == 0) { s1[wave] = sum; s2[wave] = sq; }
    __syncthreads();
    if (threadIdx.x == 0) {
        float a = 0.f, c2 = 0.f;
        #pragma unroll
        for (int w = 0; w < 4; w++) { a += s1[w]; c2 += s2[w]; }
        ws[WS_PART_SUM + b*64 + s] = a;
        ws[WS_PART_SQ  + b*64 + s] = c2;
    }
}

__global__ void finalize_stats(float* __restrict__ ws) {
    int b = threadIdx.x;
    if (b < NB) {
        float s = 0.f, q = 0.f;
        for (int i = 0; i < 64; i++) {
            s += ws[WS_PART_SUM + b*64 + i];
            q += ws[WS_PART_SQ  + b*64 + i];
        }
        const float inv = 1.f / (float)(NC * NN);
        float mu  = s * inv;
        float var = q * inv - mu * mu;
        ws[WS_MU + b]   = mu;
        ws[WS_RSTD + b] = rsqrtf(var + EPSV);
    }
}

__global__ __launch_bounds__(256) void normalize_kernel(const float* __restrict__ x,
                                                        const float* __restrict__ gamma,
                                                        const float* __restrict__ beta,
                                                        const float* __restrict__ ws,
                                                        float* __restrict__ xn) {
    size_t i = ((size_t)blockIdx.x * 256 + threadIdx.x) * 4;
    int b = (int)(i >> 19);
    int c = (int)((i >> 10) & 511);
    float mu = ws[WS_MU + b], rstd = ws[WS_RSTD + b];
    float g  = gamma[c] * rstd;
    float be = beta[c] - mu * rstd * gamma[c];
    float4 v = *(const float4*)(x + i);
    float4 o;
    o.x = v.x*g + be; o.y = v.y*g + be; o.z = v.z*g + be; o.w = v.w*g + be;
    *(float4*)(xn + i) = o;
}

// ---------------- tiled fp32 GEMM: Y[b,o,n] = sum_c X[b,c,n]*W[o,c] + bias[o] ----------------
// MODE 0: fp32 output [b][O][n] into Y.
// MODE 1: qkv epilogue -> bf16: o<512 -> QT[b,h,n,d]; o<1024 -> KT[b,h,n,d]; else V[b,h,d,n].
template<int O, int MODE>
__global__ __launch_bounds__(256) void gemm_xw(const float* __restrict__ X,
                                               const float* __restrict__ W,
                                               const float* __restrict__ bias,
                                               float* __restrict__ Y,
                                               __hip_bfloat16* __restrict__ QTo,
                                               __hip_bfloat16* __restrict__ KTo,
                                               __hip_bfloat16* __restrict__ Vo,
                                               int Cd) {
    const int NT = NN / 64;
    const int OT = O / 64;
    int nt = blockIdx.x % NT;
    int ot = (blockIdx.x / NT) % OT;
    int b  = blockIdx.x / (NT * OT);
    const float* Xb = X + (size_t)b * Cd * NN;
    __shared__ float lw[16][64];
    __shared__ float lx[16][64];
    __shared__ __hip_bfloat16 tb[64][72];
    const int t = threadIdx.x;
    const int tx = t & 15, ty = t >> 4;
    float acc[4][4] = {};
    const int o0 = ot * 64, n0 = nt * 64;
    for (int c0 = 0; c0 < Cd; c0 += 16) {
        int oo = t >> 2, k4 = (t & 3) * 4;
        float4 wv = *(const float4*)(W + (size_t)(o0 + oo) * Cd + c0 + k4);
        int kk = t >> 4, n4 = (t & 15) * 4;
        float4 xv = *(const float4*)(Xb + (size_t)(c0 + kk) * NN + n0 + n4);
        __syncthreads();
        lw[k4+0][oo] = wv.x; lw[k4+1][oo] = wv.y; lw[k4+2][oo] = wv.z; lw[k4+3][oo] = wv.w;
        *(float4*)&lx[kk][n4] = xv;
        __syncthreads();
        #pragma unroll
        for (int k2 = 0; k2 < 16; k2++) {
            float4 a  = *(const float4*)&lw[k2][ty*4];
            float4 bx = *(const float4*)&lx[k2][tx*4];
            acc[0][0]+=a.x*bx.x; acc[0][1]+=a.x*bx.y; acc[0][2]+=a.x*bx.z; acc[0][3]+=a.x*bx.w;
            acc[1][0]+=a.y*bx.x; acc[1][1]+=a.y*bx.y; acc[1][2]+=a.y*bx.z; acc[1][3]+=a.y*bx.w;
            acc[2][0]+=a.z*bx.x; acc[2][1]+=a.z*bx.y; acc[2][2]+=a.z*bx.z; acc[2][3]+=a.z*bx.w;
            acc[3][0]+=a.w*bx.x; acc[3][1]+=a.w*bx.y; acc[3][2]+=a.w*bx.z; acc[3][3]+=a.w*bx.w;
        }
    }
    // bias
    #pragma unroll
    for (int i = 0; i < 4; i++) {
        float bi = bias[o0 + ty*4 + i];
        #pragma unroll
        for (int j = 0; j < 4; j++) acc[i][j] += bi;
    }
    if (MODE == 0) {
        #pragma unroll
        for (int i = 0; i < 4; i++) {
            float4 r;
            r.x = acc[i][0]; r.y = acc[i][1]; r.z = acc[i][2]; r.w = acc[i][3];
            *(float4*)(Y + ((size_t)b * O + o0 + ty*4 + i) * NN + n0 + tx*4) = r;
        }
    } else {
        if (o0 >= 1024) {
            int h = (o0 - 1024) >> 6;
            #pragma unroll
            for (int i = 0; i < 4; i++) {
                bf16x4 v;
                #pragma unroll
                for (int j = 0; j < 4; j++) v[j] = f2bf(acc[i][j]);
                *(bf16x4*)(Vo + ((size_t)(b*8+h)*64 + ty*4 + i)*1024 + n0 + tx*4) = v;
            }
        } else {
            __hip_bfloat16* dst = (o0 < 512) ? QTo : KTo;
            int h = (o0 & 511) >> 6;
            // transpose 64x64 tile through LDS so global stores are 16B rows
            #pragma unroll
            for (int i = 0; i < 4; i++)
                #pragma unroll
                for (int j = 0; j < 4; j++)
                    tb[tx*4+j][ty*4+i] = __float2bfloat16(acc[i][j]);
            __syncthreads();
            #pragma unroll
            for (int p2 = 0; p2 < 2; p2++) {
                int idx = t + p2*256;
                int nl = idx >> 3, d8 = (idx & 7) * 8;
                *(bf16x8*)(dst + ((size_t)(b*8+h)*1024 + n0 + nl)*64 + d8) =
                    *(const bf16x8*)&tb[nl][d8];
            }
        }
    }
}

// ---------------- MFMA flash attention ----------------
// Block: (b,h) x 64-query tile; 4 waves x 16 queries. Chunks of 64 keys.
__global__ __launch_bounds__(256) void attn_mfma(const __hip_bfloat16* __restrict__ QT,
                                                 const __hip_bfloat16* __restrict__ KT,
                                                 const __hip_bfloat16* __restrict__ Vb,
                                                 float* __restrict__ vals) {
    const int qt = blockIdx.x & 15;
    const int bh = blockIdx.x >> 4;
    const int t = threadIdx.x;
    const int wv = t >> 6, lane = t & 63;
    const int g = lane >> 4, li = lane & 15;

    const __hip_bfloat16* QTg = QT + (size_t)bh * NN * 64;
    const __hip_bfloat16* KTg = KT + (size_t)bh * NN * 64;
    const __hip_bfloat16* Vg  = Vb + (size_t)bh * 64 * NN;

    __shared__ __hip_bfloat16 kt_s[64][72];
    __shared__ __hip_bfloat16 v_s[64][72];

    const int nq0 = qt*64 + wv*16;
    const float scale = 0.04419417382415922f;   // 512^-0.5

    // Q fragments (B-operand): lane holds Q[d = kslot][n = nq0+li]
    bf16x8 qf[2];
    {
        const __hip_bfloat16* qp = QTg + (size_t)(nq0 + li) * 64;
        #pragma unroll
        for (int hf = 0; hf < 2; hf++) {
            bf16x4 a = *(const bf16x4*)(qp + 32*hf + 4*g);
            bf16x4 b2 = *(const bf16x4*)(qp + 32*hf + 16 + 4*g);
            bf16x8 v;
            v[0]=a[0]; v[1]=a[1]; v[2]=a[2]; v[3]=a[3];
            v[4]=b2[0]; v[5]=b2[1]; v[6]=b2[2]; v[7]=b2[3];
            qf[hf] = v;
        }
    }

    float m_run = -1e30f, l_run = 0.f;
    f32x4 o_acc[4];
    #pragma unroll
    for (int dt = 0; dt < 4; dt++) { o_acc[dt][0]=0.f; o_acc[dt][1]=0.f; o_acc[dt][2]=0.f; o_acc[dt][3]=0.f; }

    for (int ck = 0; ck < 16; ck++) {
        const int mc0 = ck * 64;
        __syncthreads();
        #pragma unroll
        for (int p = 0; p < 2; p++) {
            int idx = t + p*256;
            int row = idx >> 3, c8 = (idx & 7) * 8;
            *(bf16x8*)&kt_s[row][c8] = *(const bf16x8*)(KTg + (size_t)(mc0+row)*64 + c8);
            *(bf16x8*)&v_s[row][c8]  = *(const bf16x8*)(Vg + (size_t)row*NN + mc0 + c8);
        }
        __syncthreads();

        // QK^T: S^T tiles, A=K-frag (rows=keys), B=Q-frag (cols=queries)
        f32x4 s_acc[4];
        #pragma unroll
        for (int mt = 0; mt < 4; mt++) {
            f32x4 c; c[0]=0.f; c[1]=0.f; c[2]=0.f; c[3]=0.f;
            #pragma unroll
            for (int hf = 0; hf < 2; hf++) {
                const __hip_bfloat16* kp = &kt_s[mt*16 + li][32*hf + 4*g];
                bf16x4 a = *(const bf16x4*)kp;
                bf16x4 b2 = *(const bf16x4*)(kp + 16);
                bf16x8 kf;
                kf[0]=a[0]; kf[1]=a[1]; kf[2]=a[2]; kf[3]=a[3];
                kf[4]=b2[0]; kf[5]=b2[1]; kf[6]=b2[2]; kf[7]=b2[3];
                c = MFMA16(kf, qf[hf], c);
            }
            s_acc[mt] = c;
        }

        // online softmax: lane holds 16 scores for query li (keys 16mt+4g+r)
        float p16[16];
        float cmax = -1e30f;
        #pragma unroll
        for (int mt = 0; mt < 4; mt++)
            #pragma unroll
            for (int r = 0; r < 4; r++) {
                float s = s_acc[mt][r] * scale;
                p16[mt*4+r] = s;
                cmax = fmaxf(cmax, s);
            }
        cmax = fmaxf(cmax, __shfl_xor(cmax, 16));
        cmax = fmaxf(cmax, __shfl_xor(cmax, 32));
        float m_new = fmaxf(m_run, cmax);
        float resc = __expf(m_run - m_new);
        float ls = 0.f;
        #pragma unroll
        for (int i = 0; i < 16; i++) { p16[i] = __expf(p16[i] - m_new); ls += p16[i]; }
        ls += __shfl_xor(ls, 16); ls += __shfl_xor(ls, 32);
        l_run = l_run * resc + ls;
        m_run = m_new;

        // rescale accumulators (row r of o_acc is query 4g+r)
        f32x4 rv;
        #pragma unroll
        for (int r = 0; r < 4; r++) rv[r] = __shfl(resc, 4*g + r);
        #pragma unroll
        for (int dt = 0; dt < 4; dt++) {
            o_acc[dt][0]*=rv[0]; o_acc[dt][1]*=rv[1]; o_acc[dt][2]*=rv[2]; o_acc[dt][3]*=rv[3];
        }

        // P fragments: k-slot (g,j) holds key 32ks + 16(j>>2) + 4g + (j&3)
        bf16x8 pf[2];
        #pragma unroll
        for (int ks = 0; ks < 2; ks++) {
            bf16x8 v;
            #pragma unroll
            for (int j = 0; j < 8; j++) v[j] = f2bf(p16[(2*ks + (j>>2))*4 + (j&3)]);
            pf[ks] = v;
        }

        // PV: A=P (rows=queries), B=V-frag (cols=d'), k=keys
        #pragma unroll
        for (int dt = 0; dt < 4; dt++) {
            #pragma unroll
            for (int ks = 0; ks < 2; ks++) {
                const __hip_bfloat16* vp = &v_s[dt*16 + li][ks*32 + 4*g];
                bf16x4 a = *(const bf16x4*)vp;
                bf16x4 b2 = *(const bf16x4*)(vp + 16);
                bf16x8 vf;
                vf[0]=a[0]; vf[1]=a[1]; vf[2]=a[2]; vf[3]=a[3];
                vf[4]=b2[0]; vf[5]=b2[1]; vf[6]=b2[2]; vf[7]=b2[3];
                o_acc[dt] = MFMA16(pf[ks], vf, o_acc[dt]);
            }
        }
    }

    // epilogue: divide by l, store; row r = query nq0+4g+r, col d' = dt*16+li
    float linv = 1.f / l_run;
    f32x4 lv;
    #pragma unroll
    for (int r = 0; r < 4; r++) lv[r] = __shfl(linv, 4*g + r);
    #pragma unroll
    for (int dt = 0; dt < 4; dt++) {
        float4 o;
        o.x = o_acc[dt][0]*lv[0]; o.y = o_acc[dt][1]*lv[1];
        o.z = o_acc[dt][2]*lv[2]; o.w = o_acc[dt][3]*lv[3];
        *(float4*)(vals + ((size_t)bh*64 + dt*16 + li)*NN + nq0 + 4*g) = o;
    }
}

extern "C" void kernel_launch(void* const* d_in, const int* in_sizes, int n_in,
                              void* d_out, int out_size, void* d_ws, size_t ws_size,
                              hipStream_t stream) {
    const float* x      = (const float*)d_in[0];
    const float* gamma  = (const float*)d_in[1];
    const float* beta   = (const float*)d_in[2];
    const float* w_qkv  = (const float*)d_in[3];
    const float* b_qkv  = (const float*)d_in[4];
    const float* w_proj = (const float*)d_in[5];
    const float* b_proj = (const float*)d_in[6];
    float* ws   = (float*)d_ws;
    float* out  = (float*)d_out;
    float* xn   = ws + WS_XN;
    float* vals = ws + WS_XN;   // reused after QKV GEMM consumes xn
    __hip_bfloat16* QT = (__hip_bfloat16*)(ws + WS_QT);
    __hip_bfloat16* KT = (__hip_bfloat16*)(ws + WS_KT);
    __hip_bfloat16* Vb = (__hip_bfloat16*)(ws + WS_V);

    reduce_partial<<<dim3(NB * 64), dim3(256), 0, stream>>>(x, ws);
    finalize_stats<<<dim3(1), dim3(64), 0, stream>>>(ws);
    normalize_kernel<<<dim3(4096), dim3(256), 0, stream>>>(x, gamma, beta, ws, xn);
    gemm_xw<OQKV, 1><<<dim3(NB * (OQKV/64) * (NN/64)), dim3(256), 0, stream>>>(
        xn, w_qkv, b_qkv, nullptr, QT, KT, Vb, NC);
    attn_mfma<<<dim3(NB * NHEADS * 16), dim3(256), 0, stream>>>(QT, KT, Vb, vals);
    gemm_xw<NC, 0><<<dim3(NB * (NC/64) * (NN/64)), dim3(256), 0, stream>>>(
        vals, w_proj, b_proj, out, nullptr, nullptr, nullptr, NC);
}

// Round 3
// 105.345 us; speedup vs baseline: 7.1391x; 2.7982x over previous
//
#include <hip/hip_runtime.h>
#include <hip/hip_bf16.h>
#include <math.h>

#define NB 8
#define NC 512
#define NN 1024      // H*W
#define NHEADS 8
#define EPSV 1e-5f

typedef __attribute__((ext_vector_type(8))) short bf16x8;
typedef __attribute__((ext_vector_type(4))) short bf16x4;
typedef __attribute__((ext_vector_type(4))) float f32x4;
typedef __attribute__((ext_vector_type(16))) float f32x16;

#define MFMA16(a,b,c) __builtin_amdgcn_mfma_f32_16x16x32_bf16(a,b,c,0,0,0)
#define MFMA32(a,b,c) __builtin_amdgcn_mfma_f32_32x32x16_bf16(a,b,c,0,0,0)

static __device__ __forceinline__ short f2bf(float f) {
    __hip_bfloat16 h = __float2bfloat16(f);
    return *reinterpret_cast<short*>(&h);
}

static __device__ __forceinline__ void gload16(const void* g, void* l) {
    __builtin_amdgcn_global_load_lds((const __attribute__((address_space(1))) void*)g,
                                     (__attribute__((address_space(3))) void*)l, 16, 0, 0);
}

// ws layout (float offsets):
#define WS_PART_SUM 0            // 512
#define WS_PART_SQ  1024         // 512
#define WS_MU       2048         // 8
#define WS_RSTD     2056         // 8
#define WS_XNT   4096                    // bf16 [8][1024][512]  = 4,194,304 bf16
#define WS_QT    (WS_XNT  + 2097152)     // bf16 [64][1024][64]
#define WS_KT    (WS_QT   + 2097152)
#define WS_V     (WS_KT   + 2097152)     // bf16 [64][64][1024]
#define WS_VALST (WS_V    + 2097152)     // bf16 [8][1024][512]
#define WS_WQB   (WS_VALST+ 2097152)     // bf16 [1536][512]
#define WS_WPB   (WS_WQB  + 393216)      // bf16 [512][512]
// end = 11,014,144 floats = 44 MB (harness ws >= 67MB per round-1 usage)

// ---------------- fp32 -> bf16 weight convert ----------------
__global__ __launch_bounds__(256) void to_bf16(const float* __restrict__ s,
                                               __hip_bfloat16* __restrict__ d, int n4) {
    int i = blockIdx.x * 256 + threadIdx.x;
    if (i < n4) {
        float4 v = ((const float4*)s)[i];
        bf16x4 w;
        w[0] = f2bf(v.x); w[1] = f2bf(v.y); w[2] = f2bf(v.z); w[3] = f2bf(v.w);
        *(bf16x4*)(d + (size_t)i*4) = w;
    }
}

// ---------------- stage 1: partial sum/sumsq per batch ----------------
__global__ __launch_bounds__(256) void reduce_partial(const float* __restrict__ x,
                                                      float* __restrict__ ws) {
    int b = blockIdx.x >> 6;
    int s = blockIdx.x & 63;
    const float* xb = x + (size_t)b * (NC * NN) + (size_t)s * 8192;
    float sum = 0.f, sq = 0.f;
    for (int i = threadIdx.x; i < 2048; i += 256) {
        float4 v = ((const float4*)xb)[i];
        sum += v.x + v.y + v.z + v.w;
        sq  += v.x*v.x + v.y*v.y + v.z*v.z + v.w*v.w;
    }
    #pragma unroll
    for (int off = 32; off; off >>= 1) {
        sum += __shfl_down(sum, off);
        sq  += __shfl_down(sq,  off);
    }
    __shared__ float s1[4], s2[4];
    int wave = threadIdx.x >> 6, lane = threadIdx.x & 63;
    if (lane == 0) { s1[wave] = sum; s2[wave] = sq; }
    __syncthreads();
    if (threadIdx.x == 0) {
        float a = 0.f, c2 = 0.f;
        #pragma unroll
        for (int w = 0; w < 4; w++) { a += s1[w]; c2 += s2[w]; }
        ws[WS_PART_SUM + b*64 + s] = a;
        ws[WS_PART_SQ  + b*64 + s] = c2;
    }
}

__global__ void finalize_stats(float* __restrict__ ws) {
    int b = threadIdx.x;
    if (b < NB) {
        float s = 0.f, q = 0.f;
        for (int i = 0; i < 64; i++) {
            s += ws[WS_PART_SUM + b*64 + i];
            q += ws[WS_PART_SQ  + b*64 + i];
        }
        const float inv = 1.f / (float)(NC * NN);
        float mu  = s * inv;
        float var = q * inv - mu * mu;
        ws[WS_MU + b]   = mu;
        ws[WS_RSTD + b] = rsqrtf(var + EPSV);
    }
}

// ---------------- normalize + transpose -> xnT[b][n][c] bf16 ----------------
__global__ __launch_bounds__(256) void normalize_t(const float* __restrict__ x,
                                                   const float* __restrict__ gamma,
                                                   const float* __restrict__ beta,
                                                   const float* __restrict__ ws,
                                                   __hip_bfloat16* __restrict__ xnT) {
    int nt = blockIdx.x & 15, ct = (blockIdx.x >> 4) & 7, b = blockIdx.x >> 7;
    __shared__ __hip_bfloat16 tb[64][72];
    float mu = ws[WS_MU + b], rstd = ws[WS_RSTD + b];
    const float* xb = x + ((size_t)b*512 + ct*64)*1024 + nt*64;
    int t = threadIdx.x;
    int cl = t >> 4, n4 = (t & 15) * 4;
    #pragma unroll
    for (int i = 0; i < 4; i++) {
        int c = i*16 + cl;
        float gm = gamma[ct*64 + c];
        float g = gm * rstd;
        float be = beta[ct*64 + c] - mu * g;
        float4 v = *(const float4*)(xb + (size_t)c*1024 + n4);
        tb[n4+0][c] = __float2bfloat16(v.x*g + be);
        tb[n4+1][c] = __float2bfloat16(v.y*g + be);
        tb[n4+2][c] = __float2bfloat16(v.z*g + be);
        tb[n4+3][c] = __float2bfloat16(v.w*g + be);
    }
    __syncthreads();
    #pragma unroll
    for (int i = 0; i < 2; i++) {
        int idx = i*256 + t;
        int n = idx >> 3, c8 = (idx & 7) * 8;
        *(bf16x8*)(xnT + ((size_t)b*1024 + nt*64 + n)*512 + ct*64 + c8) =
            *(const bf16x8*)&tb[n][c8];
    }
}

// ---------------- MFMA bf16 GEMM: Y[o][n] = sum_c A[o][c] * BxT[n][c] ----------------
// A [O][512] bf16 k-contig; Bx [b][1024][512] bf16 k-contig. Tile 128x128, BK=64.
// MODE 0: fp32 out [b][512][n] + bias. MODE 1 (qkv): sec0->QT[bh][n][d], sec1->KT, sec2->V[bh][d][n].
template<int OT, int MODE>
__global__ __launch_bounds__(256) void gemm_mfma(const __hip_bfloat16* __restrict__ Aw,
                                                 const __hip_bfloat16* __restrict__ Bx,
                                                 const float* __restrict__ bias,
                                                 float* __restrict__ Yout,
                                                 __hip_bfloat16* __restrict__ QTx,
                                                 __hip_bfloat16* __restrict__ KTx,
                                                 __hip_bfloat16* __restrict__ Vx) {
    __shared__ __align__(16) __hip_bfloat16 lds_raw[17408];  // 34816B: A(16K)+B(16K) / tb 128x136
    const int bx = blockIdx.x;
    const int nt = bx & 7;
    const int ot = (bx >> 3) % OT;
    const int bb = bx / (8 * OT);
    const int o0 = ot * 128, n0 = nt * 128;

    const int t = threadIdx.x, wv = t >> 6, l = t & 63;
    const int lr = l & 31, lh = l >> 5;
    const int wr = wv >> 1, wc = wv & 1;

    const __hip_bfloat16* Ag = Aw + (size_t)o0 * 512;
    const __hip_bfloat16* Bg = Bx + ((size_t)bb * 1024 + n0) * 512;
    __hip_bfloat16* Ab = lds_raw;            // [128][64] swizzled
    __hip_bfloat16* Bb = lds_raw + 128*64;

    f32x16 acc[2][2];
    #pragma unroll
    for (int a1 = 0; a1 < 2; a1++)
        #pragma unroll
        for (int a2 = 0; a2 < 2; a2++)
            #pragma unroll
            for (int r = 0; r < 16; r++) acc[a1][a2][r] = 0.f;

    const int srow = wv*8 + (l >> 3);          // row within 32-chunk
    const int sblk = (l & 7) ^ (l >> 3);       // pre-swizzled source block

    for (int k0 = 0; k0 < 512; k0 += 64) {
        __syncthreads();
        #pragma unroll
        for (int c = 0; c < 4; c++) {
            int row = c*32 + srow;
            gload16(Ag + (size_t)row*512 + k0 + sblk*8, Ab + (c*32 + wv*8)*64);
            gload16(Bg + (size_t)row*512 + k0 + sblk*8, Bb + (c*32 + wv*8)*64);
        }
        __syncthreads();
        #pragma unroll
        for (int ks = 0; ks < 4; ks++) {
            bf16x8 af[2], bfr[2];
            #pragma unroll
            for (int mi = 0; mi < 2; mi++) {
                int row = wr*64 + mi*32 + lr;
                af[mi] = *(const bf16x8*)(Ab + row*64 + (((ks*2 + lh) ^ (row & 7)) * 8));
            }
            #pragma unroll
            for (int ni = 0; ni < 2; ni++) {
                int row = wc*64 + ni*32 + lr;
                bfr[ni] = *(const bf16x8*)(Bb + row*64 + (((ks*2 + lh) ^ (row & 7)) * 8));
            }
            acc[0][0] = MFMA32(af[0], bfr[0], acc[0][0]);
            acc[0][1] = MFMA32(af[0], bfr[1], acc[0][1]);
            acc[1][0] = MFMA32(af[1], bfr[0], acc[1][0]);
            acc[1][1] = MFMA32(af[1], bfr[1], acc[1][1]);
        }
    }

    // C/D map (verified m74/m101): col = lr, row = (r&3) + 8*(r>>2) + 4*lh
    if (MODE == 0) {
        #pragma unroll
        for (int mi = 0; mi < 2; mi++)
            #pragma unroll
            for (int q = 0; q < 4; q++) {
                int obase = o0 + wr*64 + mi*32 + 8*q + 4*lh;
                float4 bv = *(const float4*)(bias + obase);
                #pragma unroll
                for (int ni = 0; ni < 2; ni++) {
                    int nn = n0 + wc*64 + ni*32 + lr;
                    #pragma unroll
                    for (int j = 0; j < 4; j++)
                        Yout[((size_t)bb*512 + obase + j)*1024 + nn] = acc[mi][ni][q*4+j] + bv[j];
                }
            }
    } else {
        int sec = o0 >> 9;                 // 0=Q 1=K 2=V
        if (sec == 2) {
            int od0 = o0 & 511;
            #pragma unroll
            for (int mi = 0; mi < 2; mi++)
                #pragma unroll
                for (int q = 0; q < 4; q++) {
                    int ob = wr*64 + mi*32 + 8*q + 4*lh;
                    float4 bv = *(const float4*)(bias + o0 + ob);
                    #pragma unroll
                    for (int j = 0; j < 4; j++) {
                        int ol = od0 + ob + j;
                        int h = ol >> 6, d = ol & 63;
                        __hip_bfloat16* dst = Vx + ((size_t)((bb<<3) + h)*64 + d)*1024;
                        #pragma unroll
                        for (int ni = 0; ni < 2; ni++) {
                            int nn = n0 + wc*64 + ni*32 + lr;
                            dst[nn] = __float2bfloat16(acc[mi][ni][q*4+j] + bv[j]);
                        }
                    }
                }
        } else {
            __syncthreads();   // done reading Ab/Bb; reuse LDS as transpose buffer
            __hip_bfloat16* tb = lds_raw;  // [128][136]
            #pragma unroll
            for (int mi = 0; mi < 2; mi++)
                #pragma unroll
                for (int q = 0; q < 4; q++) {
                    int ob = wr*64 + mi*32 + 8*q + 4*lh;
                    float4 bv = *(const float4*)(bias + o0 + ob);
                    #pragma unroll
                    for (int ni = 0; ni < 2; ni++) {
                        int nn = wc*64 + ni*32 + lr;
                        bf16x4 w;
                        #pragma unroll
                        for (int j = 0; j < 4; j++) w[j] = f2bf(acc[mi][ni][q*4+j] + bv[j]);
                        *(bf16x4*)&tb[(size_t)nn*136 + ob] = w;
                    }
                }
            __syncthreads();
            __hip_bfloat16* dst0 = (sec == 0) ? QTx : KTx;
            int h0 = (o0 & 511) >> 6;
            #pragma unroll
            for (int i = 0; i < 8; i++) {
                int idx = i*256 + t;
                int n = idx >> 4, rem = idx & 15;
                int hh = rem >> 3, d8 = (rem & 7) * 8;
                *(bf16x8*)(dst0 + ((size_t)((bb<<3) + h0 + hh)*1024 + n0 + n)*64 + d8) =
                    *(const bf16x8*)&tb[(size_t)n*136 + hh*64 + d8];
            }
        }
    }
}

// ---------------- MFMA flash attention (as round 2) ----------------
__global__ __launch_bounds__(256) void attn_mfma(const __hip_bfloat16* __restrict__ QT,
                                                 const __hip_bfloat16* __restrict__ KT,
                                                 const __hip_bfloat16* __restrict__ Vb,
                                                 __hip_bfloat16* __restrict__ valsT) {
    const int qt = blockIdx.x & 15;
    const int bh = blockIdx.x >> 4;
    const int t = threadIdx.x;
    const int wv = t >> 6, lane = t & 63;
    const int g = lane >> 4, li = lane & 15;

    const __hip_bfloat16* QTg = QT + (size_t)bh * NN * 64;
    const __hip_bfloat16* KTg = KT + (size_t)bh * NN * 64;
    const __hip_bfloat16* Vg  = Vb + (size_t)bh * 64 * NN;

    __shared__ __hip_bfloat16 kt_s[64][72];
    __shared__ __hip_bfloat16 v_s[64][72];

    const int nq0 = qt*64 + wv*16;
    const float scale = 0.04419417382415922f;   // 512^-0.5

    bf16x8 qf[2];
    {
        const __hip_bfloat16* qp = QTg + (size_t)(nq0 + li) * 64;
        #pragma unroll
        for (int hf = 0; hf < 2; hf++) {
            bf16x4 a = *(const bf16x4*)(qp + 32*hf + 4*g);
            bf16x4 b2 = *(const bf16x4*)(qp + 32*hf + 16 + 4*g);
            bf16x8 v;
            v[0]=a[0]; v[1]=a[1]; v[2]=a[2]; v[3]=a[3];
            v[4]=b2[0]; v[5]=b2[1]; v[6]=b2[2]; v[7]=b2[3];
            qf[hf] = v;
        }
    }

    float m_run = -1e30f, l_run = 0.f;
    f32x4 o_acc[4];
    #pragma unroll
    for (int dt = 0; dt < 4; dt++) { o_acc[dt][0]=0.f; o_acc[dt][1]=0.f; o_acc[dt][2]=0.f; o_acc[dt][3]=0.f; }

    for (int ck = 0; ck < 16; ck++) {
        const int mc0 = ck * 64;
        __syncthreads();
        #pragma unroll
        for (int p = 0; p < 2; p++) {
            int idx = t + p*256;
            int row = idx >> 3, c8 = (idx & 7) * 8;
            *(bf16x8*)&kt_s[row][c8] = *(const bf16x8*)(KTg + (size_t)(mc0+row)*64 + c8);
            *(bf16x8*)&v_s[row][c8]  = *(const bf16x8*)(Vg + (size_t)row*NN + mc0 + c8);
        }
        __syncthreads();

        f32x4 s_acc[4];
        #pragma unroll
        for (int mt = 0; mt < 4; mt++) {
            f32x4 c; c[0]=0.f; c[1]=0.f; c[2]=0.f; c[3]=0.f;
            #pragma unroll
            for (int hf = 0; hf < 2; hf++) {
                const __hip_bfloat16* kp = &kt_s[mt*16 + li][32*hf + 4*g];
                bf16x4 a = *(const bf16x4*)kp;
                bf16x4 b2 = *(const bf16x4*)(kp + 16);
                bf16x8 kf;
                kf[0]=a[0]; kf[1]=a[1]; kf[2]=a[2]; kf[3]=a[3];
                kf[4]=b2[0]; kf[5]=b2[1]; kf[6]=b2[2]; kf[7]=b2[3];
                c = MFMA16(kf, qf[hf], c);
            }
            s_acc[mt] = c;
        }

        float p16[16];
        float cmax = -1e30f;
        #pragma unroll
        for (int mt = 0; mt < 4; mt++)
            #pragma unroll
            for (int r = 0; r < 4; r++) {
                float s = s_acc[mt][r] * scale;
                p16[mt*4+r] = s;
                cmax = fmaxf(cmax, s);
            }
        cmax = fmaxf(cmax, __shfl_xor(cmax, 16));
        cmax = fmaxf(cmax, __shfl_xor(cmax, 32));
        float m_new = fmaxf(m_run, cmax);
        float resc = __expf(m_run - m_new);
        float ls = 0.f;
        #pragma unroll
        for (int i = 0; i < 16; i++) { p16[i] = __expf(p16[i] - m_new); ls += p16[i]; }
        ls += __shfl_xor(ls, 16); ls += __shfl_xor(ls, 32);
        l_run = l_run * resc + ls;
        m_run = m_new;

        f32x4 rv;
        #pragma unroll
        for (int r = 0; r < 4; r++) rv[r] = __shfl(resc, 4*g + r);
        #pragma unroll
        for (int dt = 0; dt < 4; dt++) {
            o_acc[dt][0]*=rv[0]; o_acc[dt][1]*=rv[1]; o_acc[dt][2]*=rv[2]; o_acc[dt][3]*=rv[3];
        }

        bf16x8 pf[2];
        #pragma unroll
        for (int ks = 0; ks < 2; ks++) {
            bf16x8 v;
            #pragma unroll
            for (int j = 0; j < 8; j++) v[j] = f2bf(p16[(2*ks + (j>>2))*4 + (j&3)]);
            pf[ks] = v;
        }

        #pragma unroll
        for (int dt = 0; dt < 4; dt++) {
            #pragma unroll
            for (int ks = 0; ks < 2; ks++) {
                const __hip_bfloat16* vp = &v_s[dt*16 + li][ks*32 + 4*g];
                bf16x4 a = *(const bf16x4*)vp;
                bf16x4 b2 = *(const bf16x4*)(vp + 16);
                bf16x8 vf;
                vf[0]=a[0]; vf[1]=a[1]; vf[2]=a[2]; vf[3]=a[3];
                vf[4]=b2[0]; vf[5]=b2[1]; vf[6]=b2[2]; vf[7]=b2[3];
                o_acc[dt] = MFMA16(pf[ks], vf, o_acc[dt]);
            }
        }
    }

    float linv = 1.f / l_run;
    f32x4 lv;
    #pragma unroll
    for (int r = 0; r < 4; r++) lv[r] = __shfl(linv, 4*g + r);
    const int bI = bh >> 3, hI = bh & 7;
    __hip_bfloat16* vt = valsT + (size_t)bI*1024*512 + hI*64;
    #pragma unroll
    for (int dt = 0; dt < 4; dt++)
        #pragma unroll
        for (int r = 0; r < 4; r++)
            vt[(size_t)(nq0 + 4*g + r)*512 + dt*16 + li] = __float2bfloat16(o_acc[dt][r]*lv[r]);
}

extern "C" void kernel_launch(void* const* d_in, const int* in_sizes, int n_in,
                              void* d_out, int out_size, void* d_ws, size_t ws_size,
                              hipStream_t stream) {
    const float* x      = (const float*)d_in[0];
    const float* gamma  = (const float*)d_in[1];
    const float* beta   = (const float*)d_in[2];
    const float* w_qkv  = (const float*)d_in[3];
    const float* b_qkv  = (const float*)d_in[4];
    const float* w_proj = (const float*)d_in[5];
    const float* b_proj = (const float*)d_in[6];
    float* ws   = (float*)d_ws;
    float* out  = (float*)d_out;
    __hip_bfloat16* xnT   = (__hip_bfloat16*)(ws + WS_XNT);
    __hip_bfloat16* QT    = (__hip_bfloat16*)(ws + WS_QT);
    __hip_bfloat16* KT    = (__hip_bfloat16*)(ws + WS_KT);
    __hip_bfloat16* Vx    = (__hip_bfloat16*)(ws + WS_V);
    __hip_bfloat16* valsT = (__hip_bfloat16*)(ws + WS_VALST);
    __hip_bfloat16* wqb   = (__hip_bfloat16*)(ws + WS_WQB);
    __hip_bfloat16* wpb   = (__hip_bfloat16*)(ws + WS_WPB);

    to_bf16<<<dim3(768), dim3(256), 0, stream>>>(w_qkv, wqb, 196608);
    to_bf16<<<dim3(256), dim3(256), 0, stream>>>(w_proj, wpb, 65536);
    reduce_partial<<<dim3(NB*64), dim3(256), 0, stream>>>(x, ws);
    finalize_stats<<<dim3(1), dim3(64), 0, stream>>>(ws);
    normalize_t<<<dim3(1024), dim3(256), 0, stream>>>(x, gamma, beta, ws, xnT);
    gemm_mfma<12, 1><<<dim3(768), dim3(256), 0, stream>>>(wqb, xnT, b_qkv,
                                                          nullptr, QT, KT, Vx);
    attn_mfma<<<dim3(1024), dim3(256), 0, stream>>>(QT, KT, Vx, valsT);
    gemm_mfma<4, 0><<<dim3(256), dim3(256), 0, stream>>>(wpb, valsT, b_proj,
                                                         out, nullptr, nullptr, nullptr);
}

// Round 4
// 98.196 us; speedup vs baseline: 7.6589x; 1.0728x over previous
//
#include <hip/hip_runtime.h>
#include <hip/hip_bf16.h>
#include <math.h>

#define NB 8
#define NC 512
#define NN 1024      // H*W
#define NHEADS 8
#define EPSV 1e-5f

typedef __attribute__((ext_vector_type(8))) short bf16x8;
typedef __attribute__((ext_vector_type(4))) short bf16x4;
typedef __attribute__((ext_vector_type(4))) float f32x4;
typedef __attribute__((ext_vector_type(16))) float f32x16;

#define MFMA16(a,b,c) __builtin_amdgcn_mfma_f32_16x16x32_bf16(a,b,c,0,0,0)
#define MFMA32(a,b,c) __builtin_amdgcn_mfma_f32_32x32x16_bf16(a,b,c,0,0,0)

static __device__ __forceinline__ short f2bf(float f) {
    __hip_bfloat16 h = __float2bfloat16(f);
    return *reinterpret_cast<short*>(&h);
}

static __device__ __forceinline__ void gload16(const void* g, void* l) {
    __builtin_amdgcn_global_load_lds((const __attribute__((address_space(1))) void*)g,
                                     (__attribute__((address_space(3))) void*)l, 16, 0, 0);
}

// ws layout (float offsets):
#define WS_PART_SUM 0            // 512
#define WS_PART_SQ  1024         // 512
#define WS_MU       2048         // 8
#define WS_RSTD     2056         // 8
#define WS_XNT   4096                    // bf16 [8][1024][512]
#define WS_QT    (WS_XNT  + 2097152)     // bf16 [64][1024][64]  (d fragment-permuted)
#define WS_KT    (WS_QT   + 2097152)     // bf16 [64][1024][64]  (d fragment-permuted)
#define WS_V     (WS_KT   + 2097152)     // bf16 [64][64][1024]  (keys permuted within 64-groups)
#define WS_VALST (WS_V    + 2097152)     // bf16 [8][1024][512]
#define WS_WQB   (WS_VALST+ 2097152)     // bf16 [1536][512]
#define WS_WPB   (WS_WQB  + 393216)      // bf16 [512][512]

// ---------------- fp32 -> bf16 weight convert ----------------
__global__ __launch_bounds__(256) void to_bf16(const float* __restrict__ s,
                                               __hip_bfloat16* __restrict__ d, int n4) {
    int i = blockIdx.x * 256 + threadIdx.x;
    if (i < n4) {
        float4 v = ((const float4*)s)[i];
        bf16x4 w;
        w[0] = f2bf(v.x); w[1] = f2bf(v.y); w[2] = f2bf(v.z); w[3] = f2bf(v.w);
        *(bf16x4*)(d + (size_t)i*4) = w;
    }
}

// ---------------- stage 1: partial sum/sumsq per batch ----------------
__global__ __launch_bounds__(256) void reduce_partial(const float* __restrict__ x,
                                                      float* __restrict__ ws) {
    int b = blockIdx.x >> 6;
    int s = blockIdx.x & 63;
    const float* xb = x + (size_t)b * (NC * NN) + (size_t)s * 8192;
    float sum = 0.f, sq = 0.f;
    for (int i = threadIdx.x; i < 2048; i += 256) {
        float4 v = ((const float4*)xb)[i];
        sum += v.x + v.y + v.z + v.w;
        sq  += v.x*v.x + v.y*v.y + v.z*v.z + v.w*v.w;
    }
    #pragma unroll
    for (int off = 32; off; off >>= 1) {
        sum += __shfl_down(sum, off);
        sq  += __shfl_down(sq,  off);
    }
    __shared__ float s1[4], s2[4];
    int wave = threadIdx.x >> 6, lane = threadIdx.x & 63;
    if (lane == 0) { s1[wave] = sum; s2[wave] = sq; }
    __syncthreads();
    if (threadIdx.x == 0) {
        float a = 0.f, c2 = 0.f;
        #pragma unroll
        for (int w = 0; w < 4; w++) { a += s1[w]; c2 += s2[w]; }
        ws[WS_PART_SUM + b*64 + s] = a;
        ws[WS_PART_SQ  + b*64 + s] = c2;
    }
}

__global__ void finalize_stats(float* __restrict__ ws) {
    int b = threadIdx.x;
    if (b < NB) {
        float s = 0.f, q = 0.f;
        for (int i = 0; i < 64; i++) {
            s += ws[WS_PART_SUM + b*64 + i];
            q += ws[WS_PART_SQ  + b*64 + i];
        }
        const float inv = 1.f / (float)(NC * NN);
        float mu  = s * inv;
        float var = q * inv - mu * mu;
        ws[WS_MU + b]   = mu;
        ws[WS_RSTD + b] = rsqrtf(var + EPSV);
    }
}

// ---------------- normalize + transpose -> xnT[b][n][c] bf16 ----------------
__global__ __launch_bounds__(256) void normalize_t(const float* __restrict__ x,
                                                   const float* __restrict__ gamma,
                                                   const float* __restrict__ beta,
                                                   const float* __restrict__ ws,
                                                   __hip_bfloat16* __restrict__ xnT) {
    int nt = blockIdx.x & 15, ct = (blockIdx.x >> 4) & 7, b = blockIdx.x >> 7;
    __shared__ __hip_bfloat16 tb[64][72];
    float mu = ws[WS_MU + b], rstd = ws[WS_RSTD + b];
    const float* xb = x + ((size_t)b*512 + ct*64)*1024 + nt*64;
    int t = threadIdx.x;
    int cl = t >> 4, n4 = (t & 15) * 4;
    #pragma unroll
    for (int i = 0; i < 4; i++) {
        int c = i*16 + cl;
        float gm = gamma[ct*64 + c];
        float g = gm * rstd;
        float be = beta[ct*64 + c] - mu * g;
        float4 v = *(const float4*)(xb + (size_t)c*1024 + n4);
        tb[n4+0][c] = __float2bfloat16(v.x*g + be);
        tb[n4+1][c] = __float2bfloat16(v.y*g + be);
        tb[n4+2][c] = __float2bfloat16(v.z*g + be);
        tb[n4+3][c] = __float2bfloat16(v.w*g + be);
    }
    __syncthreads();
    #pragma unroll
    for (int i = 0; i < 2; i++) {
        int idx = i*256 + t;
        int n = idx >> 3, c8 = (idx & 7) * 8;
        *(bf16x8*)(xnT + ((size_t)b*1024 + nt*64 + n)*512 + ct*64 + c8) =
            *(const bf16x8*)&tb[n][c8];
    }
}

// ---------------- MFMA bf16 GEMM: Y[o][n] = sum_c A[o][c] * BxT[n][c] ----------------
template<int OT, int MODE>
__global__ __launch_bounds__(256) void gemm_mfma(const __hip_bfloat16* __restrict__ Aw,
                                                 const __hip_bfloat16* __restrict__ Bx,
                                                 const float* __restrict__ bias,
                                                 float* __restrict__ Yout,
                                                 __hip_bfloat16* __restrict__ QTx,
                                                 __hip_bfloat16* __restrict__ KTx,
                                                 __hip_bfloat16* __restrict__ Vx) {
    __shared__ __align__(16) __hip_bfloat16 lds_raw[17408];
    const int bx = blockIdx.x;
    const int nt = bx & 7;
    const int ot = (bx >> 3) % OT;
    const int bb = bx / (8 * OT);
    const int o0 = ot * 128, n0 = nt * 128;

    const int t = threadIdx.x, wv = t >> 6, l = t & 63;
    const int lr = l & 31, lh = l >> 5;
    const int wr = wv >> 1, wc = wv & 1;

    const __hip_bfloat16* Ag = Aw + (size_t)o0 * 512;
    const __hip_bfloat16* Bg = Bx + ((size_t)bb * 1024 + n0) * 512;
    __hip_bfloat16* Ab = lds_raw;
    __hip_bfloat16* Bb = lds_raw + 128*64;

    f32x16 acc[2][2];
    #pragma unroll
    for (int a1 = 0; a1 < 2; a1++)
        #pragma unroll
        for (int a2 = 0; a2 < 2; a2++)
            #pragma unroll
            for (int r = 0; r < 16; r++) acc[a1][a2][r] = 0.f;

    const int srow = wv*8 + (l >> 3);
    const int sblk = (l & 7) ^ (l >> 3);

    for (int k0 = 0; k0 < 512; k0 += 64) {
        __syncthreads();
        #pragma unroll
        for (int c = 0; c < 4; c++) {
            int row = c*32 + srow;
            gload16(Ag + (size_t)row*512 + k0 + sblk*8, Ab + (c*32 + wv*8)*64);
            gload16(Bg + (size_t)row*512 + k0 + sblk*8, Bb + (c*32 + wv*8)*64);
        }
        __syncthreads();
        #pragma unroll
        for (int ks = 0; ks < 4; ks++) {
            bf16x8 af[2], bfr[2];
            #pragma unroll
            for (int mi = 0; mi < 2; mi++) {
                int row = wr*64 + mi*32 + lr;
                af[mi] = *(const bf16x8*)(Ab + row*64 + (((ks*2 + lh) ^ (row & 7)) * 8));
            }
            #pragma unroll
            for (int ni = 0; ni < 2; ni++) {
                int row = wc*64 + ni*32 + lr;
                bfr[ni] = *(const bf16x8*)(Bb + row*64 + (((ks*2 + lh) ^ (row & 7)) * 8));
            }
            acc[0][0] = MFMA32(af[0], bfr[0], acc[0][0]);
            acc[0][1] = MFMA32(af[0], bfr[1], acc[0][1]);
            acc[1][0] = MFMA32(af[1], bfr[0], acc[1][0]);
            acc[1][1] = MFMA32(af[1], bfr[1], acc[1][1]);
        }
    }

    // C/D map (verified m74/m101): col = lr, row = (r&3) + 8*(r>>2) + 4*lh
    if (MODE == 0) {
        #pragma unroll
        for (int mi = 0; mi < 2; mi++)
            #pragma unroll
            for (int q = 0; q < 4; q++) {
                int obase = o0 + wr*64 + mi*32 + 8*q + 4*lh;
                float4 bv = *(const float4*)(bias + obase);
                #pragma unroll
                for (int ni = 0; ni < 2; ni++) {
                    int nn = n0 + wc*64 + ni*32 + lr;
                    #pragma unroll
                    for (int j = 0; j < 4; j++)
                        Yout[((size_t)bb*512 + obase + j)*1024 + nn] = acc[mi][ni][q*4+j] + bv[j];
                }
            }
    } else {
        int sec = o0 >> 9;                 // 0=Q 1=K 2=V
        if (sec == 2) {
            int od0 = o0 & 511;
            // permute keys within 64-groups: m=32ks+16u+4g+j -> p=32ks+8g+4u+j
            int mperm = ((lr & 12) << 1) + ((lr & 16) >> 2) + (lr & 3);
            #pragma unroll
            for (int mi = 0; mi < 2; mi++)
                #pragma unroll
                for (int q = 0; q < 4; q++) {
                    int ob = wr*64 + mi*32 + 8*q + 4*lh;
                    float4 bv = *(const float4*)(bias + o0 + ob);
                    #pragma unroll
                    for (int j = 0; j < 4; j++) {
                        int ol = od0 + ob + j;
                        int h = ol >> 6, d = ol & 63;
                        __hip_bfloat16* dst = Vx + ((size_t)((bb<<3) + h)*64 + d)*1024;
                        #pragma unroll
                        for (int ni = 0; ni < 2; ni++) {
                            int nn = n0 + wc*64 + ni*32 + mperm;
                            dst[nn] = __float2bfloat16(acc[mi][ni][q*4+j] + bv[j]);
                        }
                    }
                }
        } else {
            __syncthreads();
            __hip_bfloat16* tb = lds_raw;  // [128][136]
            #pragma unroll
            for (int mi = 0; mi < 2; mi++)
                #pragma unroll
                for (int q = 0; q < 4; q++) {
                    int ob = wr*64 + mi*32 + 8*q + 4*lh;
                    float4 bv = *(const float4*)(bias + o0 + ob);
                    #pragma unroll
                    for (int ni = 0; ni < 2; ni++) {
                        int nn = wc*64 + ni*32 + lr;
                        bf16x4 w;
                        #pragma unroll
                        for (int j = 0; j < 4; j++) w[j] = f2bf(acc[mi][ni][q*4+j] + bv[j]);
                        *(bf16x4*)&tb[(size_t)nn*136 + ob] = w;
                    }
                }
            __syncthreads();
            __hip_bfloat16* dst0 = (sec == 0) ? QTx : KTx;
            int h0 = (o0 & 511) >> 6;
            // d-permuted store: position-group slot holds logical d {32hf+4g+j, 32hf+16+4g+j}
            #pragma unroll
            for (int i = 0; i < 8; i++) {
                int idx = i*256 + t;
                int n = idx >> 4, rem = idx & 15;
                int hh = rem >> 3, slot = rem & 7;
                int hf32 = (slot & 4) << 3;
                int g4   = (slot & 3) << 2;
                bf16x4 lo = *(const bf16x4*)&tb[(size_t)n*136 + hh*64 + hf32 + g4];
                bf16x4 hi = *(const bf16x4*)&tb[(size_t)n*136 + hh*64 + hf32 + 16 + g4];
                bf16x8 w;
                w[0]=lo[0]; w[1]=lo[1]; w[2]=lo[2]; w[3]=lo[3];
                w[4]=hi[0]; w[5]=hi[1]; w[6]=hi[2]; w[7]=hi[3];
                *(bf16x8*)(dst0 + ((size_t)((bb<<3) + h0 + hh)*1024 + n0 + n)*64 + slot*8) = w;
            }
        }
    }
}

// ---------------- MFMA flash attention, 2-phase dbuf + swizzled gload_lds ----------------
__global__ __launch_bounds__(256) void attn_mfma(const __hip_bfloat16* __restrict__ QT,
                                                 const __hip_bfloat16* __restrict__ KT,
                                                 const __hip_bfloat16* __restrict__ Vb,
                                                 __hip_bfloat16* __restrict__ valsT) {
    // XCD-grouped decomposition: all 16 q-tiles of one (b,h) share an XCD
    const int bh = ((blockIdx.x & 7) << 3) | ((blockIdx.x >> 3) & 7);
    const int qt = blockIdx.x >> 6;
    const int t = threadIdx.x;
    const int wv = t >> 6, lane = t & 63;
    const int g = lane >> 4, li = lane & 15;

    const __hip_bfloat16* QTg = QT + (size_t)bh * NN * 64;
    const __hip_bfloat16* KTg = KT + (size_t)bh * NN * 64;
    const __hip_bfloat16* Vg  = Vb + (size_t)bh * 64 * NN;

    __shared__ __align__(16) __hip_bfloat16 k_ls[2*4096];
    __shared__ __align__(16) __hip_bfloat16 v_ls[2*4096];

    const int nq0 = qt*64 + wv*16;
    const float scale2 = 0.04419417382415922f * 1.4426950408889634f;  // 512^-.5 * log2(e)

    // Q fragments: d already fragment-permuted in global -> contiguous 16B per frag
    bf16x8 qf[2];
    {
        const __hip_bfloat16* qp = QTg + (size_t)(nq0 + li) * 64;
        qf[0] = *(const bf16x8*)(qp + 8*g);
        qf[1] = *(const bf16x8*)(qp + 32 + 8*g);
    }

    float m_run = -1e30f, l_run = 0.f;
    f32x4 o_acc[4];
    #pragma unroll
    for (int dt = 0; dt < 4; dt++) { o_acc[dt][0]=0.f; o_acc[dt][1]=0.f; o_acc[dt][2]=0.f; o_acc[dt][3]=0.f; }

    // stage chunk into buffer: linear LDS dest, inverse-swizzled global source (slot ^= row&7)
    auto STAGE = [&](int buf, int ck) {
        const int mc0 = ck * 64;
        __hip_bfloat16* kb = k_ls + buf*4096;
        __hip_bfloat16* vb = v_ls + buf*4096;
        #pragma unroll
        for (int p = 0; p < 2; p++) {
            int idx = t + p*256;
            int row = idx >> 3, sl = idx & 7;
            int sk = sl ^ (row & 7);
            gload16(KTg + (size_t)(mc0+row)*64 + sk*8, kb + idx*8);
            gload16(Vg + (size_t)row*NN + mc0 + sk*8, vb + idx*8);
        }
    };

    STAGE(0, 0);
    __syncthreads();
    int cur = 0;

    for (int ck = 0; ck < 16; ck++) {
        if (ck < 15) STAGE(cur ^ 1, ck + 1);

        const __hip_bfloat16* kb = k_ls + cur*4096;
        const __hip_bfloat16* vb = v_ls + cur*4096;

        // QK^T (S^T): A=K-frag rows=keys, B=Q-frag cols=queries
        f32x4 s_acc[4];
        #pragma unroll
        for (int mt = 0; mt < 4; mt++) {
            f32x4 c; c[0]=0.f; c[1]=0.f; c[2]=0.f; c[3]=0.f;
            #pragma unroll
            for (int hf = 0; hf < 2; hf++) {
                int row = mt*16 + li;
                int sl = ((hf<<2) + g) ^ (li & 7);
                bf16x8 kf = *(const bf16x8*)(kb + row*64 + sl*8);
                c = MFMA16(kf, qf[hf], c);
            }
            s_acc[mt] = c;
        }

        // online softmax in log2 domain; lane holds 16 scores for query li
        float p16[16];
        float cmax = -1e30f;
        #pragma unroll
        for (int mt = 0; mt < 4; mt++)
            #pragma unroll
            for (int r = 0; r < 4; r++) {
                float s = s_acc[mt][r] * scale2;
                p16[mt*4+r] = s;
                cmax = fmaxf(cmax, s);
            }
        cmax = fmaxf(cmax, __shfl_xor(cmax, 16));
        cmax = fmaxf(cmax, __shfl_xor(cmax, 32));
        if (!__all(cmax <= m_run + 8.0f)) {       // defer-max (T13), THR=8 in log2
            float m_new = fmaxf(m_run, cmax);
            float resc = exp2f(m_run - m_new);
            l_run *= resc;
            f32x4 rv;
            #pragma unroll
            for (int r = 0; r < 4; r++) rv[r] = __shfl(resc, 4*g + r);
            #pragma unroll
            for (int dt = 0; dt < 4; dt++) {
                o_acc[dt][0]*=rv[0]; o_acc[dt][1]*=rv[1]; o_acc[dt][2]*=rv[2]; o_acc[dt][3]*=rv[3];
            }
            m_run = m_new;
        }
        float ls = 0.f;
        #pragma unroll
        for (int i = 0; i < 16; i++) { p16[i] = exp2f(p16[i] - m_run); ls += p16[i]; }
        ls += __shfl_xor(ls, 16); ls += __shfl_xor(ls, 32);
        l_run += ls;

        // P fragments: slot order matches V's key permutation
        bf16x8 pf[2];
        #pragma unroll
        for (int ks = 0; ks < 2; ks++) {
            bf16x8 v;
            #pragma unroll
            for (int j = 0; j < 8; j++) v[j] = f2bf(p16[(2*ks + (j>>2))*4 + (j&3)]);
            pf[ks] = v;
        }

        // PV: A=P rows=queries, B=V-frag cols=d'
        #pragma unroll
        for (int dt = 0; dt < 4; dt++) {
            #pragma unroll
            for (int ks = 0; ks < 2; ks++) {
                int row = dt*16 + li;
                int sl = ((ks<<2) + g) ^ (li & 7);
                bf16x8 vf = *(const bf16x8*)(vb + row*64 + sl*8);
                o_acc[dt] = MFMA16(pf[ks], vf, o_acc[dt]);
            }
        }

        __syncthreads();   // staged data ready + everyone done reading cur
        cur ^= 1;
    }

    float linv = 1.f / l_run;
    f32x4 lv;
    #pragma unroll
    for (int r = 0; r < 4; r++) lv[r] = __shfl(linv, 4*g + r);
    const int bI = bh >> 3, hI = bh & 7;
    __hip_bfloat16* vt = valsT + (size_t)bI*1024*512 + hI*64;
    #pragma unroll
    for (int dt = 0; dt < 4; dt++)
        #pragma unroll
        for (int r = 0; r < 4; r++)
            vt[(size_t)(nq0 + 4*g + r)*512 + dt*16 + li] = __float2bfloat16(o_acc[dt][r]*lv[r]);
}

extern "C" void kernel_launch(void* const* d_in, const int* in_sizes, int n_in,
                              void* d_out, int out_size, void* d_ws, size_t ws_size,
                              hipStream_t stream) {
    const float* x      = (const float*)d_in[0];
    const float* gamma  = (const float*)d_in[1];
    const float* beta   = (const float*)d_in[2];
    const float* w_qkv  = (const float*)d_in[3];
    const float* b_qkv  = (const float*)d_in[4];
    const float* w_proj = (const float*)d_in[5];
    const float* b_proj = (const float*)d_in[6];
    float* ws   = (float*)d_ws;
    float* out  = (float*)d_out;
    __hip_bfloat16* xnT   = (__hip_bfloat16*)(ws + WS_XNT);
    __hip_bfloat16* QT    = (__hip_bfloat16*)(ws + WS_QT);
    __hip_bfloat16* KT    = (__hip_bfloat16*)(ws + WS_KT);
    __hip_bfloat16* Vx    = (__hip_bfloat16*)(ws + WS_V);
    __hip_bfloat16* valsT = (__hip_bfloat16*)(ws + WS_VALST);
    __hip_bfloat16* wqb   = (__hip_bfloat16*)(ws + WS_WQB);
    __hip_bfloat16* wpb   = (__hip_bfloat16*)(ws + WS_WPB);

    to_bf16<<<dim3(768), dim3(256), 0, stream>>>(w_qkv, wqb, 196608);
    to_bf16<<<dim3(256), dim3(256), 0, stream>>>(w_proj, wpb, 65536);
    reduce_partial<<<dim3(NB*64), dim3(256), 0, stream>>>(x, ws);
    finalize_stats<<<dim3(1), dim3(64), 0, stream>>>(ws);
    normalize_t<<<dim3(1024), dim3(256), 0, stream>>>(x, gamma, beta, ws, xnT);
    gemm_mfma<12, 1><<<dim3(768), dim3(256), 0, stream>>>(wqb, xnT, b_qkv,
                                                          nullptr, QT, KT, Vx);
    attn_mfma<<<dim3(1024), dim3(256), 0, stream>>>(QT, KT, Vx, valsT);
    gemm_mfma<4, 0><<<dim3(256), dim3(256), 0, stream>>>(wpb, valsT, b_proj,
                                                         out, nullptr, nullptr, nullptr);
}

// Round 5
// 94.662 us; speedup vs baseline: 7.9448x; 1.0373x over previous
//
#include <hip/hip_runtime.h>
#include <hip/hip_bf16.h>
#include <math.h>

#define NB 8
#define NC 512
#define NN 1024      // H*W
#define NHEADS 8
#define EPSV 1e-5f
#define SC2F 0.06376351307f   // 512^-0.5 * log2(e)

typedef __attribute__((ext_vector_type(8))) short bf16x8;
typedef __attribute__((ext_vector_type(4))) short bf16x4;
typedef __attribute__((ext_vector_type(4))) float f32x4;
typedef __attribute__((ext_vector_type(16))) float f32x16;

#define MFMA16(a,b,c) __builtin_amdgcn_mfma_f32_16x16x32_bf16(a,b,c,0,0,0)
#define MFMA32(a,b,c) __builtin_amdgcn_mfma_f32_32x32x16_bf16(a,b,c,0,0,0)

static __device__ __forceinline__ short f2bf(float f) {
    __hip_bfloat16 h = __float2bfloat16(f);
    return *reinterpret_cast<short*>(&h);
}

static __device__ __forceinline__ void gload16(const void* g, void* l) {
    __builtin_amdgcn_global_load_lds((const __attribute__((address_space(1))) void*)g,
                                     (__attribute__((address_space(3))) void*)l, 16, 0, 0);
}

// ws layout (float offsets):
#define WS_PART_SUM 0            // 512
#define WS_PART_SQ  1024         // 512
#define WS_MU       2048         // 8
#define WS_RSTD     2056         // 8
#define WS_XNT   4096                    // bf16 [8][1024][512]
#define WS_QT    (WS_XNT  + 2097152)     // bf16 [64][1024][64]  (d fragment-permuted, pre-scaled)
#define WS_KT    (WS_QT   + 2097152)     // bf16 [64][1024][64]  (d fragment-permuted)
#define WS_V     (WS_KT   + 2097152)     // bf16 [64][64][1024]  (keys permuted within 64-groups)
#define WS_VALST (WS_V    + 2097152)     // bf16 [8][1024][512]
#define WS_WQB   (WS_VALST+ 2097152)     // bf16 [1536][512]
#define WS_WPB   (WS_WQB  + 393216)      // bf16 [512][512]

// ---------------- fp32 -> bf16 weight convert (both weights, one launch) ----------------
__global__ __launch_bounds__(256) void to_bf16_both(const float* __restrict__ wq,
                                                    __hip_bfloat16* __restrict__ dq,
                                                    const float* __restrict__ wp,
                                                    __hip_bfloat16* __restrict__ dp) {
    int i = blockIdx.x * 256 + threadIdx.x;   // 0..262143
    const float* s;
    __hip_bfloat16* d;
    if (i < 196608) { s = wq; d = dq; }
    else            { s = wp; d = dp; i -= 196608; }
    float4 v = ((const float4*)s)[i];
    bf16x4 w;
    w[0] = f2bf(v.x); w[1] = f2bf(v.y); w[2] = f2bf(v.z); w[3] = f2bf(v.w);
    *(bf16x4*)(d + (size_t)i*4) = w;
}

// ---------------- stage 1: partial sum/sumsq per batch ----------------
__global__ __launch_bounds__(256) void reduce_partial(const float* __restrict__ x,
                                                      float* __restrict__ ws) {
    int b = blockIdx.x >> 6;
    int s = blockIdx.x & 63;
    const float* xb = x + (size_t)b * (NC * NN) + (size_t)s * 8192;
    float sum = 0.f, sq = 0.f;
    for (int i = threadIdx.x; i < 2048; i += 256) {
        float4 v = ((const float4*)xb)[i];
        sum += v.x + v.y + v.z + v.w;
        sq  += v.x*v.x + v.y*v.y + v.z*v.z + v.w*v.w;
    }
    #pragma unroll
    for (int off = 32; off; off >>= 1) {
        sum += __shfl_down(sum, off);
        sq  += __shfl_down(sq,  off);
    }
    __shared__ float s1[4], s2[4];
    int wave = threadIdx.x >> 6, lane = threadIdx.x & 63;
    if (lane == 0) { s1[wave] = sum; s2[wave] = sq; }
    __syncthreads();
    if (threadIdx.x == 0) {
        float a = 0.f, c2 = 0.f;
        #pragma unroll
        for (int w = 0; w < 4; w++) { a += s1[w]; c2 += s2[w]; }
        ws[WS_PART_SUM + b*64 + s] = a;
        ws[WS_PART_SQ  + b*64 + s] = c2;
    }
}

__global__ void finalize_stats(float* __restrict__ ws) {
    int b = threadIdx.x;
    if (b < NB) {
        float s = 0.f, q = 0.f;
        for (int i = 0; i < 64; i++) {
            s += ws[WS_PART_SUM + b*64 + i];
            q += ws[WS_PART_SQ  + b*64 + i];
        }
        const float inv = 1.f / (float)(NC * NN);
        float mu  = s * inv;
        float var = q * inv - mu * mu;
        ws[WS_MU + b]   = mu;
        ws[WS_RSTD + b] = rsqrtf(var + EPSV);
    }
}

// ---------------- normalize + transpose -> xnT[b][n][c] bf16 ----------------
__global__ __launch_bounds__(256) void normalize_t(const float* __restrict__ x,
                                                   const float* __restrict__ gamma,
                                                   const float* __restrict__ beta,
                                                   const float* __restrict__ ws,
                                                   __hip_bfloat16* __restrict__ xnT) {
    int nt = blockIdx.x & 15, ct = (blockIdx.x >> 4) & 7, b = blockIdx.x >> 7;
    __shared__ __hip_bfloat16 tb[64][72];
    float mu = ws[WS_MU + b], rstd = ws[WS_RSTD + b];
    const float* xb = x + ((size_t)b*512 + ct*64)*1024 + nt*64;
    int t = threadIdx.x;
    int cl = t >> 4, n4 = (t & 15) * 4;
    #pragma unroll
    for (int i = 0; i < 4; i++) {
        int c = i*16 + cl;
        float gm = gamma[ct*64 + c];
        float g = gm * rstd;
        float be = beta[ct*64 + c] - mu * g;
        float4 v = *(const float4*)(xb + (size_t)c*1024 + n4);
        tb[n4+0][c] = __float2bfloat16(v.x*g + be);
        tb[n4+1][c] = __float2bfloat16(v.y*g + be);
        tb[n4+2][c] = __float2bfloat16(v.z*g + be);
        tb[n4+3][c] = __float2bfloat16(v.w*g + be);
    }
    __syncthreads();
    #pragma unroll
    for (int i = 0; i < 2; i++) {
        int idx = i*256 + t;
        int n = idx >> 3, c8 = (idx & 7) * 8;
        *(bf16x8*)(xnT + ((size_t)b*1024 + nt*64 + n)*512 + ct*64 + c8) =
            *(const bf16x8*)&tb[n][c8];
    }
}

// ---------------- MFMA bf16 GEMM: Y[o][n] = sum_c A[o][c] * BxT[n][c] ----------------
template<int OT, int MODE>
__global__ __launch_bounds__(256) void gemm_mfma(const __hip_bfloat16* __restrict__ Aw,
                                                 const __hip_bfloat16* __restrict__ Bx,
                                                 const float* __restrict__ bias,
                                                 float* __restrict__ Yout,
                                                 __hip_bfloat16* __restrict__ QTx,
                                                 __hip_bfloat16* __restrict__ KTx,
                                                 __hip_bfloat16* __restrict__ Vx) {
    __shared__ __align__(16) __hip_bfloat16 lds_raw[17408];
    const int bx = blockIdx.x;
    const int nt = bx & 7;
    const int ot = (bx >> 3) % OT;
    const int bb = bx / (8 * OT);
    const int o0 = ot * 128, n0 = nt * 128;

    const int t = threadIdx.x, wv = t >> 6, l = t & 63;
    const int lr = l & 31, lh = l >> 5;
    const int wr = wv >> 1, wc = wv & 1;

    const __hip_bfloat16* Ag = Aw + (size_t)o0 * 512;
    const __hip_bfloat16* Bg = Bx + ((size_t)bb * 1024 + n0) * 512;
    __hip_bfloat16* Ab = lds_raw;
    __hip_bfloat16* Bb = lds_raw + 128*64;

    f32x16 acc[2][2];
    #pragma unroll
    for (int a1 = 0; a1 < 2; a1++)
        #pragma unroll
        for (int a2 = 0; a2 < 2; a2++)
            #pragma unroll
            for (int r = 0; r < 16; r++) acc[a1][a2][r] = 0.f;

    const int srow = wv*8 + (l >> 3);
    const int sblk = (l & 7) ^ (l >> 3);

    for (int k0 = 0; k0 < 512; k0 += 64) {
        __syncthreads();
        #pragma unroll
        for (int c = 0; c < 4; c++) {
            int row = c*32 + srow;
            gload16(Ag + (size_t)row*512 + k0 + sblk*8, Ab + (c*32 + wv*8)*64);
            gload16(Bg + (size_t)row*512 + k0 + sblk*8, Bb + (c*32 + wv*8)*64);
        }
        __syncthreads();
        #pragma unroll
        for (int ks = 0; ks < 4; ks++) {
            bf16x8 af[2], bfr[2];
            #pragma unroll
            for (int mi = 0; mi < 2; mi++) {
                int row = wr*64 + mi*32 + lr;
                af[mi] = *(const bf16x8*)(Ab + row*64 + (((ks*2 + lh) ^ (row & 7)) * 8));
            }
            #pragma unroll
            for (int ni = 0; ni < 2; ni++) {
                int row = wc*64 + ni*32 + lr;
                bfr[ni] = *(const bf16x8*)(Bb + row*64 + (((ks*2 + lh) ^ (row & 7)) * 8));
            }
            acc[0][0] = MFMA32(af[0], bfr[0], acc[0][0]);
            acc[0][1] = MFMA32(af[0], bfr[1], acc[0][1]);
            acc[1][0] = MFMA32(af[1], bfr[0], acc[1][0]);
            acc[1][1] = MFMA32(af[1], bfr[1], acc[1][1]);
        }
    }

    // C/D map (verified m74/m101): col = lr, row = (r&3) + 8*(r>>2) + 4*lh
    if (MODE == 0) {
        #pragma unroll
        for (int mi = 0; mi < 2; mi++)
            #pragma unroll
            for (int q = 0; q < 4; q++) {
                int obase = o0 + wr*64 + mi*32 + 8*q + 4*lh;
                float4 bv = *(const float4*)(bias + obase);
                #pragma unroll
                for (int ni = 0; ni < 2; ni++) {
                    int nn = n0 + wc*64 + ni*32 + lr;
                    #pragma unroll
                    for (int j = 0; j < 4; j++)
                        Yout[((size_t)bb*512 + obase + j)*1024 + nn] = acc[mi][ni][q*4+j] + bv[j];
                }
            }
    } else {
        int sec = o0 >> 9;                 // 0=Q 1=K 2=V
        if (sec == 2) {
            int od0 = o0 & 511;
            // permute keys within 64-groups: m=32ks+16u+4g+j -> p=32ks+8g+4u+j
            int mperm = ((lr & 12) << 1) + ((lr & 16) >> 2) + (lr & 3);
            #pragma unroll
            for (int mi = 0; mi < 2; mi++)
                #pragma unroll
                for (int q = 0; q < 4; q++) {
                    int ob = wr*64 + mi*32 + 8*q + 4*lh;
                    float4 bv = *(const float4*)(bias + o0 + ob);
                    #pragma unroll
                    for (int j = 0; j < 4; j++) {
                        int ol = od0 + ob + j;
                        int h = ol >> 6, d = ol & 63;
                        __hip_bfloat16* dst = Vx + ((size_t)((bb<<3) + h)*64 + d)*1024;
                        #pragma unroll
                        for (int ni = 0; ni < 2; ni++) {
                            int nn = n0 + wc*64 + ni*32 + mperm;
                            dst[nn] = __float2bfloat16(acc[mi][ni][q*4+j] + bv[j]);
                        }
                    }
                }
        } else {
            // Q gets pre-scaled by 512^-0.5*log2(e) so attention skips the scale mul
            const float qs = (sec == 0) ? SC2F : 1.0f;
            __syncthreads();
            __hip_bfloat16* tb = lds_raw;  // [128][136]
            #pragma unroll
            for (int mi = 0; mi < 2; mi++)
                #pragma unroll
                for (int q = 0; q < 4; q++) {
                    int ob = wr*64 + mi*32 + 8*q + 4*lh;
                    float4 bv = *(const float4*)(bias + o0 + ob);
                    #pragma unroll
                    for (int ni = 0; ni < 2; ni++) {
                        int nn = wc*64 + ni*32 + lr;
                        bf16x4 w;
                        #pragma unroll
                        for (int j = 0; j < 4; j++) w[j] = f2bf((acc[mi][ni][q*4+j] + bv[j]) * qs);
                        *(bf16x4*)&tb[(size_t)nn*136 + ob] = w;
                    }
                }
            __syncthreads();
            __hip_bfloat16* dst0 = (sec == 0) ? QTx : KTx;
            int h0 = (o0 & 511) >> 6;
            // d-permuted store: position-group slot holds logical d {32hf+4g+j, 32hf+16+4g+j}
            #pragma unroll
            for (int i = 0; i < 8; i++) {
                int idx = i*256 + t;
                int n = idx >> 4, rem = idx & 15;
                int hh = rem >> 3, slot = rem & 7;
                int hf32 = (slot & 4) << 3;
                int g4   = (slot & 3) << 2;
                bf16x4 lo = *(const bf16x4*)&tb[(size_t)n*136 + hh*64 + hf32 + g4];
                bf16x4 hi = *(const bf16x4*)&tb[(size_t)n*136 + hh*64 + hf32 + 16 + g4];
                bf16x8 w;
                w[0]=lo[0]; w[1]=lo[1]; w[2]=lo[2]; w[3]=lo[3];
                w[4]=hi[0]; w[5]=hi[1]; w[6]=hi[2]; w[7]=hi[3];
                *(bf16x8*)(dst0 + ((size_t)((bb<<3) + h0 + hh)*1024 + n0 + n)*64 + slot*8) = w;
            }
        }
    }
}

// ---------------- MFMA flash attention, VALU-trimmed softmax ----------------
__global__ __launch_bounds__(256) void attn_mfma(const __hip_bfloat16* __restrict__ QT,
                                                 const __hip_bfloat16* __restrict__ KT,
                                                 const __hip_bfloat16* __restrict__ Vb,
                                                 __hip_bfloat16* __restrict__ valsT) {
    // XCD-grouped decomposition: all 16 q-tiles of one (b,h) share an XCD
    const int bh = ((blockIdx.x & 7) << 3) | ((blockIdx.x >> 3) & 7);
    const int qt = blockIdx.x >> 6;
    const int t = threadIdx.x;
    const int wv = t >> 6, lane = t & 63;
    const int g = lane >> 4, li = lane & 15;

    const __hip_bfloat16* QTg = QT + (size_t)bh * NN * 64;
    const __hip_bfloat16* KTg = KT + (size_t)bh * NN * 64;
    const __hip_bfloat16* Vg  = Vb + (size_t)bh * 64 * NN;

    __shared__ __align__(16) __hip_bfloat16 k_ls[2*4096];
    __shared__ __align__(16) __hip_bfloat16 v_ls[2*4096];

    const int nq0 = qt*64 + wv*16;

    // Q fragments: pre-scaled + fragment-permuted in global
    bf16x8 qf[2];
    {
        const __hip_bfloat16* qp = QTg + (size_t)(nq0 + li) * 64;
        qf[0] = *(const bf16x8*)(qp + 8*g);
        qf[1] = *(const bf16x8*)(qp + 32 + 8*g);
    }

    // all-ones B fragment (bf16 1.0) for the l row-sum MFMA
    bf16x8 onesf;
    #pragma unroll
    for (int j = 0; j < 8; j++) onesf[j] = (short)0x3F80;

    float m_run = -1e30f;
    f32x4 o_acc[4], o_l;
    #pragma unroll
    for (int dt = 0; dt < 4; dt++) { o_acc[dt][0]=0.f; o_acc[dt][1]=0.f; o_acc[dt][2]=0.f; o_acc[dt][3]=0.f; }
    o_l[0]=0.f; o_l[1]=0.f; o_l[2]=0.f; o_l[3]=0.f;

    auto STAGE = [&](int buf, int ck) {
        const int mc0 = ck * 64;
        __hip_bfloat16* kb = k_ls + buf*4096;
        __hip_bfloat16* vb = v_ls + buf*4096;
        #pragma unroll
        for (int p = 0; p < 2; p++) {
            int idx = t + p*256;
            int row = idx >> 3, sl = idx & 7;
            int sk = sl ^ (row & 7);
            gload16(KTg + (size_t)(mc0+row)*64 + sk*8, kb + idx*8);
            gload16(Vg + (size_t)row*NN + mc0 + sk*8, vb + idx*8);
        }
    };

    STAGE(0, 0);
    __syncthreads();
    int cur = 0;

    for (int ck = 0; ck < 16; ck++) {
        if (ck < 15) STAGE(cur ^ 1, ck + 1);

        const __hip_bfloat16* kb = k_ls + cur*4096;
        const __hip_bfloat16* vb = v_ls + cur*4096;

        // QK^T (S^T): A=K-frag rows=keys, B=Q-frag cols=queries (already log2-scaled)
        f32x4 s_acc[4];
        __builtin_amdgcn_s_setprio(1);
        #pragma unroll
        for (int mt = 0; mt < 4; mt++) {
            f32x4 c; c[0]=0.f; c[1]=0.f; c[2]=0.f; c[3]=0.f;
            #pragma unroll
            for (int hf = 0; hf < 2; hf++) {
                int row = mt*16 + li;
                int sl = ((hf<<2) + g) ^ (li & 7);
                bf16x8 kf = *(const bf16x8*)(kb + row*64 + sl*8);
                c = MFMA16(kf, qf[hf], c);
            }
            s_acc[mt] = c;
        }
        __builtin_amdgcn_s_setprio(0);

        // online softmax (log2 domain); lane holds 16 scores for query li
        float p16[16];
        #pragma unroll
        for (int mt = 0; mt < 4; mt++)
            #pragma unroll
            for (int r = 0; r < 4; r++) p16[mt*4+r] = s_acc[mt][r];
        // pairwise max tree (fuses to v_max3)
        float mx[8];
        #pragma unroll
        for (int i = 0; i < 8; i++) mx[i] = fmaxf(p16[i], p16[i+8]);
        #pragma unroll
        for (int i = 0; i < 4; i++) mx[i] = fmaxf(mx[i], mx[i+4]);
        float cmax = fmaxf(fmaxf(mx[0], mx[1]), fmaxf(mx[2], mx[3]));
        cmax = fmaxf(cmax, __shfl_xor(cmax, 16));
        cmax = fmaxf(cmax, __shfl_xor(cmax, 32));
        if (!__all(cmax <= m_run + 8.0f)) {       // defer-max (T13), THR=8 in log2
            float m_new = fmaxf(m_run, cmax);
            float resc = exp2f(m_run - m_new);
            f32x4 rv;
            #pragma unroll
            for (int r = 0; r < 4; r++) rv[r] = __shfl(resc, 4*g + r);
            #pragma unroll
            for (int dt = 0; dt < 4; dt++) {
                o_acc[dt][0]*=rv[0]; o_acc[dt][1]*=rv[1]; o_acc[dt][2]*=rv[2]; o_acc[dt][3]*=rv[3];
            }
            o_l[0]*=rv[0]; o_l[1]*=rv[1]; o_l[2]*=rv[2]; o_l[3]*=rv[3];
            m_run = m_new;
        }
        #pragma unroll
        for (int i = 0; i < 16; i++) p16[i] = exp2f(p16[i] - m_run);

        // P fragments: slot order matches V's key permutation
        bf16x8 pf[2];
        #pragma unroll
        for (int ks = 0; ks < 2; ks++) {
            bf16x8 v;
            #pragma unroll
            for (int j = 0; j < 8; j++) v[j] = f2bf(p16[(2*ks + (j>>2))*4 + (j&3)]);
            pf[ks] = v;
        }

        // PV + l row-sum: A=P rows=queries; B=V-frag cols=d' / all-ones
        __builtin_amdgcn_s_setprio(1);
        #pragma unroll
        for (int dt = 0; dt < 4; dt++) {
            #pragma unroll
            for (int ks = 0; ks < 2; ks++) {
                int row = dt*16 + li;
                int sl = ((ks<<2) + g) ^ (li & 7);
                bf16x8 vf = *(const bf16x8*)(vb + row*64 + sl*8);
                o_acc[dt] = MFMA16(pf[ks], vf, o_acc[dt]);
            }
        }
        o_l = MFMA16(pf[0], onesf, o_l);
        o_l = MFMA16(pf[1], onesf, o_l);
        __builtin_amdgcn_s_setprio(0);

        __syncthreads();   // staged data ready + everyone done reading cur
        cur ^= 1;
    }

    // epilogue: out = o_acc / o_l (row r = query nq0+4g+r, lane-local l)
    f32x4 lv;
    #pragma unroll
    for (int r = 0; r < 4; r++) lv[r] = 1.0f / o_l[r];
    const int bI = bh >> 3, hI = bh & 7;
    __hip_bfloat16* vt = valsT + (size_t)bI*1024*512 + hI*64;
    #pragma unroll
    for (int dt = 0; dt < 4; dt++)
        #pragma unroll
        for (int r = 0; r < 4; r++)
            vt[(size_t)(nq0 + 4*g + r)*512 + dt*16 + li] = __float2bfloat16(o_acc[dt][r]*lv[r]);
}

extern "C" void kernel_launch(void* const* d_in, const int* in_sizes, int n_in,
                              void* d_out, int out_size, void* d_ws, size_t ws_size,
                              hipStream_t stream) {
    const float* x      = (const float*)d_in[0];
    const float* gamma  = (const float*)d_in[1];
    const float* beta   = (const float*)d_in[2];
    const float* w_qkv  = (const float*)d_in[3];
    const float* b_qkv  = (const float*)d_in[4];
    const float* w_proj = (const float*)d_in[5];
    const float* b_proj = (const float*)d_in[6];
    float* ws   = (float*)d_ws;
    float* out  = (float*)d_out;
    __hip_bfloat16* xnT   = (__hip_bfloat16*)(ws + WS_XNT);
    __hip_bfloat16* QT    = (__hip_bfloat16*)(ws + WS_QT);
    __hip_bfloat16* KT    = (__hip_bfloat16*)(ws + WS_KT);
    __hip_bfloat16* Vx    = (__hip_bfloat16*)(ws + WS_V);
    __hip_bfloat16* valsT = (__hip_bfloat16*)(ws + WS_VALST);
    __hip_bfloat16* wqb   = (__hip_bfloat16*)(ws + WS_WQB);
    __hip_bfloat16* wpb   = (__hip_bfloat16*)(ws + WS_WPB);

    to_bf16_both<<<dim3(1024), dim3(256), 0, stream>>>(w_qkv, wqb, w_proj, wpb);
    reduce_partial<<<dim3(NB*64), dim3(256), 0, stream>>>(x, ws);
    finalize_stats<<<dim3(1), dim3(64), 0, stream>>>(ws);
    normalize_t<<<dim3(1024), dim3(256), 0, stream>>>(x, gamma, beta, ws, xnT);
    gemm_mfma<12, 1><<<dim3(768), dim3(256), 0, stream>>>(wqb, xnT, b_qkv,
                                                          nullptr, QT, KT, Vx);
    attn_mfma<<<dim3(1024), dim3(256), 0, stream>>>(QT, KT, Vx, valsT);
    gemm_mfma<4, 0><<<dim3(256), dim3(256), 0, stream>>>(wpb, valsT, b_proj,
                                                         out, nullptr, nullptr, nullptr);
}

// Round 6
// 86.826 us; speedup vs baseline: 8.6618x; 1.0902x over previous
//
#include <hip/hip_runtime.h>
#include <hip/hip_bf16.h>
#include <math.h>

#define NB 8
#define NC 512
#define NN 1024      // H*W
#define NHEADS 8
#define EPSV 1e-5f
#define SC2F 0.06376351307f   // 512^-0.5 * log2(e)

typedef __attribute__((ext_vector_type(8))) short bf16x8;
typedef __attribute__((ext_vector_type(4))) short bf16x4;
typedef __attribute__((ext_vector_type(4))) float f32x4;
typedef __attribute__((ext_vector_type(16))) float f32x16;

#define MFMA16(a,b,c) __builtin_amdgcn_mfma_f32_16x16x32_bf16(a,b,c,0,0,0)
#define MFMA32(a,b,c) __builtin_amdgcn_mfma_f32_32x32x16_bf16(a,b,c,0,0,0)

static __device__ __forceinline__ short f2bf(float f) {
    __hip_bfloat16 h = __float2bfloat16(f);
    return *reinterpret_cast<short*>(&h);
}

static __device__ __forceinline__ unsigned cvt_pk_bf16(float lo, float hi) {
    unsigned r;
    asm("v_cvt_pk_bf16_f32 %0, %1, %2" : "=v"(r) : "v"(lo), "v"(hi));
    return r;
}

static __device__ __forceinline__ void gload16(const void* g, void* l) {
    __builtin_amdgcn_global_load_lds((const __attribute__((address_space(1))) void*)g,
                                     (__attribute__((address_space(3))) void*)l, 16, 0, 0);
}

// ws layout (float offsets):
#define WS_PART_SUM 0            // 512
#define WS_PART_SQ  1024         // 512
#define WS_MU       2048         // 8
#define WS_RSTD     2056         // 8
#define WS_XNT   4096                    // bf16 [8][1024][512]
#define WS_QT    (WS_XNT  + 2097152)     // bf16 [64][1024][64]  (d fragment-permuted, pre-scaled)
#define WS_KT    (WS_QT   + 2097152)     // bf16 [64][1024][64]  (d fragment-permuted)
#define WS_V     (WS_KT   + 2097152)     // bf16 [64][64][1024]  (keys permuted within 64-groups)
#define WS_VALST (WS_V    + 2097152)     // bf16 [8][1024][512]
#define WS_WQB   (WS_VALST+ 2097152)     // bf16 [1536][512]
#define WS_WPB   (WS_WQB  + 393216)      // bf16 [512][512]

// ---------------- fp32 -> bf16 weight convert (both weights, one launch) ----------------
__global__ __launch_bounds__(256) void to_bf16_both(const float* __restrict__ wq,
                                                    __hip_bfloat16* __restrict__ dq,
                                                    const float* __restrict__ wp,
                                                    __hip_bfloat16* __restrict__ dp) {
    int i = blockIdx.x * 256 + threadIdx.x;   // 0..262143
    const float* s;
    __hip_bfloat16* d;
    if (i < 196608) { s = wq; d = dq; }
    else            { s = wp; d = dp; i -= 196608; }
    float4 v = ((const float4*)s)[i];
    bf16x4 w;
    w[0] = f2bf(v.x); w[1] = f2bf(v.y); w[2] = f2bf(v.z); w[3] = f2bf(v.w);
    *(bf16x4*)(d + (size_t)i*4) = w;
}

// ---------------- stage 1: partial sum/sumsq per batch ----------------
__global__ __launch_bounds__(256) void reduce_partial(const float* __restrict__ x,
                                                      float* __restrict__ ws) {
    int b = blockIdx.x >> 6;
    int s = blockIdx.x & 63;
    const float* xb = x + (size_t)b * (NC * NN) + (size_t)s * 8192;
    float sum = 0.f, sq = 0.f;
    for (int i = threadIdx.x; i < 2048; i += 256) {
        float4 v = ((const float4*)xb)[i];
        sum += v.x + v.y + v.z + v.w;
        sq  += v.x*v.x + v.y*v.y + v.z*v.z + v.w*v.w;
    }
    #pragma unroll
    for (int off = 32; off; off >>= 1) {
        sum += __shfl_down(sum, off);
        sq  += __shfl_down(sq,  off);
    }
    __shared__ float s1[4], s2[4];
    int wave = threadIdx.x >> 6, lane = threadIdx.x & 63;
    if (lane == 0) { s1[wave] = sum; s2[wave] = sq; }
    __syncthreads();
    if (threadIdx.x == 0) {
        float a = 0.f, c2 = 0.f;
        #pragma unroll
        for (int w = 0; w < 4; w++) { a += s1[w]; c2 += s2[w]; }
        ws[WS_PART_SUM + b*64 + s] = a;
        ws[WS_PART_SQ  + b*64 + s] = c2;
    }
}

__global__ void finalize_stats(float* __restrict__ ws) {
    int b = threadIdx.x;
    if (b < NB) {
        float s = 0.f, q = 0.f;
        for (int i = 0; i < 64; i++) {
            s += ws[WS_PART_SUM + b*64 + i];
            q += ws[WS_PART_SQ  + b*64 + i];
        }
        const float inv = 1.f / (float)(NC * NN);
        float mu  = s * inv;
        float var = q * inv - mu * mu;
        ws[WS_MU + b]   = mu;
        ws[WS_RSTD + b] = rsqrtf(var + EPSV);
    }
}

// ---------------- normalize + transpose -> xnT[b][n][c] bf16 ----------------
__global__ __launch_bounds__(256) void normalize_t(const float* __restrict__ x,
                                                   const float* __restrict__ gamma,
                                                   const float* __restrict__ beta,
                                                   const float* __restrict__ ws,
                                                   __hip_bfloat16* __restrict__ xnT) {
    int nt = blockIdx.x & 15, ct = (blockIdx.x >> 4) & 7, b = blockIdx.x >> 7;
    __shared__ __hip_bfloat16 tb[64][72];
    float mu = ws[WS_MU + b], rstd = ws[WS_RSTD + b];
    const float* xb = x + ((size_t)b*512 + ct*64)*1024 + nt*64;
    int t = threadIdx.x;
    int cl = t >> 4, n4 = (t & 15) * 4;
    #pragma unroll
    for (int i = 0; i < 4; i++) {
        int c = i*16 + cl;
        float gm = gamma[ct*64 + c];
        float g = gm * rstd;
        float be = beta[ct*64 + c] - mu * g;
        float4 v = *(const float4*)(xb + (size_t)c*1024 + n4);
        tb[n4+0][c] = __float2bfloat16(v.x*g + be);
        tb[n4+1][c] = __float2bfloat16(v.y*g + be);
        tb[n4+2][c] = __float2bfloat16(v.z*g + be);
        tb[n4+3][c] = __float2bfloat16(v.w*g + be);
    }
    __syncthreads();
    #pragma unroll
    for (int i = 0; i < 2; i++) {
        int idx = i*256 + t;
        int n = idx >> 3, c8 = (idx & 7) * 8;
        *(bf16x8*)(xnT + ((size_t)b*1024 + nt*64 + n)*512 + ct*64 + c8) =
            *(const bf16x8*)&tb[n][c8];
    }
}

// ---------------- MFMA bf16 GEMM: Y[o][n] = sum_c A[o][c] * BxT[n][c] ----------------
template<int OT, int MODE>
__global__ __launch_bounds__(256) void gemm_mfma(const __hip_bfloat16* __restrict__ Aw,
                                                 const __hip_bfloat16* __restrict__ Bx,
                                                 const float* __restrict__ bias,
                                                 float* __restrict__ Yout,
                                                 __hip_bfloat16* __restrict__ QTx,
                                                 __hip_bfloat16* __restrict__ KTx,
                                                 __hip_bfloat16* __restrict__ Vx) {
    __shared__ __align__(16) __hip_bfloat16 lds_raw[17408];
    // batch-affinity XCD swizzle: all blocks of batch bb land on XCD bb
    // (grid = 8*OT*8, %8==0 -> bijective). B-panel (1MB) + A (<=1.5MB) go L2-resident.
    const int bx = blockIdx.x;
    const int swz = (bx & 7) * (OT * 8) + (bx >> 3);
    const int nt = swz & 7;
    const int ot = (swz >> 3) % OT;
    const int bb = swz / (8 * OT);
    const int o0 = ot * 128, n0 = nt * 128;

    const int t = threadIdx.x, wv = t >> 6, l = t & 63;
    const int lr = l & 31, lh = l >> 5;
    const int wr = wv >> 1, wc = wv & 1;

    const __hip_bfloat16* Ag = Aw + (size_t)o0 * 512;
    const __hip_bfloat16* Bg = Bx + ((size_t)bb * 1024 + n0) * 512;
    __hip_bfloat16* Ab = lds_raw;
    __hip_bfloat16* Bb = lds_raw + 128*64;

    f32x16 acc[2][2];
    #pragma unroll
    for (int a1 = 0; a1 < 2; a1++)
        #pragma unroll
        for (int a2 = 0; a2 < 2; a2++)
            #pragma unroll
            for (int r = 0; r < 16; r++) acc[a1][a2][r] = 0.f;

    const int srow = wv*8 + (l >> 3);
    const int sblk = (l & 7) ^ (l >> 3);

    for (int k0 = 0; k0 < 512; k0 += 64) {
        __syncthreads();
        #pragma unroll
        for (int c = 0; c < 4; c++) {
            int row = c*32 + srow;
            gload16(Ag + (size_t)row*512 + k0 + sblk*8, Ab + (c*32 + wv*8)*64);
            gload16(Bg + (size_t)row*512 + k0 + sblk*8, Bb + (c*32 + wv*8)*64);
        }
        __syncthreads();
        #pragma unroll
        for (int ks = 0; ks < 4; ks++) {
            bf16x8 af[2], bfr[2];
            #pragma unroll
            for (int mi = 0; mi < 2; mi++) {
                int row = wr*64 + mi*32 + lr;
                af[mi] = *(const bf16x8*)(Ab + row*64 + (((ks*2 + lh) ^ (row & 7)) * 8));
            }
            #pragma unroll
            for (int ni = 0; ni < 2; ni++) {
                int row = wc*64 + ni*32 + lr;
                bfr[ni] = *(const bf16x8*)(Bb + row*64 + (((ks*2 + lh) ^ (row & 7)) * 8));
            }
            acc[0][0] = MFMA32(af[0], bfr[0], acc[0][0]);
            acc[0][1] = MFMA32(af[0], bfr[1], acc[0][1]);
            acc[1][0] = MFMA32(af[1], bfr[0], acc[1][0]);
            acc[1][1] = MFMA32(af[1], bfr[1], acc[1][1]);
        }
    }

    // C/D map (verified m74/m101): col = lr, row = (r&3) + 8*(r>>2) + 4*lh
    if (MODE == 0) {
        #pragma unroll
        for (int mi = 0; mi < 2; mi++)
            #pragma unroll
            for (int q = 0; q < 4; q++) {
                int obase = o0 + wr*64 + mi*32 + 8*q + 4*lh;
                float4 bv = *(const float4*)(bias + obase);
                #pragma unroll
                for (int ni = 0; ni < 2; ni++) {
                    int nn = n0 + wc*64 + ni*32 + lr;
                    #pragma unroll
                    for (int j = 0; j < 4; j++)
                        Yout[((size_t)bb*512 + obase + j)*1024 + nn] = acc[mi][ni][q*4+j] + bv[j];
                }
            }
    } else {
        int sec = o0 >> 9;                 // 0=Q 1=K 2=V
        if (sec == 2) {
            int od0 = o0 & 511;
            // permute keys within 64-groups: m=32ks+16u+4g+j -> p=32ks+8g+4u+j
            int mperm = ((lr & 12) << 1) + ((lr & 16) >> 2) + (lr & 3);
            #pragma unroll
            for (int mi = 0; mi < 2; mi++)
                #pragma unroll
                for (int q = 0; q < 4; q++) {
                    int ob = wr*64 + mi*32 + 8*q + 4*lh;
                    float4 bv = *(const float4*)(bias + o0 + ob);
                    #pragma unroll
                    for (int j = 0; j < 4; j++) {
                        int ol = od0 + ob + j;
                        int h = ol >> 6, d = ol & 63;
                        __hip_bfloat16* dst = Vx + ((size_t)((bb<<3) + h)*64 + d)*1024;
                        #pragma unroll
                        for (int ni = 0; ni < 2; ni++) {
                            int nn = n0 + wc*64 + ni*32 + mperm;
                            dst[nn] = __float2bfloat16(acc[mi][ni][q*4+j] + bv[j]);
                        }
                    }
                }
        } else {
            // Q gets pre-scaled by 512^-0.5*log2(e) so attention skips the scale mul
            const float qs = (sec == 0) ? SC2F : 1.0f;
            __syncthreads();
            __hip_bfloat16* tb = lds_raw;  // [128][136]
            #pragma unroll
            for (int mi = 0; mi < 2; mi++)
                #pragma unroll
                for (int q = 0; q < 4; q++) {
                    int ob = wr*64 + mi*32 + 8*q + 4*lh;
                    float4 bv = *(const float4*)(bias + o0 + ob);
                    #pragma unroll
                    for (int ni = 0; ni < 2; ni++) {
                        int nn = wc*64 + ni*32 + lr;
                        bf16x4 w;
                        #pragma unroll
                        for (int j = 0; j < 4; j++) w[j] = f2bf((acc[mi][ni][q*4+j] + bv[j]) * qs);
                        *(bf16x4*)&tb[(size_t)nn*136 + ob] = w;
                    }
                }
            __syncthreads();
            __hip_bfloat16* dst0 = (sec == 0) ? QTx : KTx;
            int h0 = (o0 & 511) >> 6;
            // d-permuted store: position-group slot holds logical d {32hf+4g+j, 32hf+16+4g+j}
            #pragma unroll
            for (int i = 0; i < 8; i++) {
                int idx = i*256 + t;
                int n = idx >> 4, rem = idx & 15;
                int hh = rem >> 3, slot = rem & 7;
                int hf32 = (slot & 4) << 3;
                int g4   = (slot & 3) << 2;
                bf16x4 lo = *(const bf16x4*)&tb[(size_t)n*136 + hh*64 + hf32 + g4];
                bf16x4 hi = *(const bf16x4*)&tb[(size_t)n*136 + hh*64 + hf32 + 16 + g4];
                bf16x8 w;
                w[0]=lo[0]; w[1]=lo[1]; w[2]=lo[2]; w[3]=lo[3];
                w[4]=hi[0]; w[5]=hi[1]; w[6]=hi[2]; w[7]=hi[3];
                *(bf16x8*)(dst0 + ((size_t)((bb<<3) + h0 + hh)*1024 + n0 + n)*64 + slot*8) = w;
            }
        }
    }
}

// ---------------- MFMA flash attention, cvt_pk + raw exp2 softmax ----------------
__global__ __launch_bounds__(256) void attn_mfma(const __hip_bfloat16* __restrict__ QT,
                                                 const __hip_bfloat16* __restrict__ KT,
                                                 const __hip_bfloat16* __restrict__ Vb,
                                                 __hip_bfloat16* __restrict__ valsT) {
    // XCD-grouped decomposition: all 16 q-tiles of one (b,h) share an XCD
    const int bh = ((blockIdx.x & 7) << 3) | ((blockIdx.x >> 3) & 7);
    const int qt = blockIdx.x >> 6;
    const int t = threadIdx.x;
    const int wv = t >> 6, lane = t & 63;
    const int g = lane >> 4, li = lane & 15;

    const __hip_bfloat16* QTg = QT + (size_t)bh * NN * 64;
    const __hip_bfloat16* KTg = KT + (size_t)bh * NN * 64;
    const __hip_bfloat16* Vg  = Vb + (size_t)bh * 64 * NN;

    __shared__ __align__(16) __hip_bfloat16 k_ls[2*4096];
    __shared__ __align__(16) __hip_bfloat16 v_ls[2*4096];

    const int nq0 = qt*64 + wv*16;

    // Q fragments: pre-scaled + fragment-permuted in global
    bf16x8 qf[2];
    {
        const __hip_bfloat16* qp = QTg + (size_t)(nq0 + li) * 64;
        qf[0] = *(const bf16x8*)(qp + 8*g);
        qf[1] = *(const bf16x8*)(qp + 32 + 8*g);
    }

    // all-ones B fragment (bf16 1.0) for the l row-sum MFMA
    bf16x8 onesf;
    #pragma unroll
    for (int j = 0; j < 8; j++) onesf[j] = (short)0x3F80;

    float m_run = -1e30f;
    f32x4 o_acc[4], o_l;
    #pragma unroll
    for (int dt = 0; dt < 4; dt++) { o_acc[dt][0]=0.f; o_acc[dt][1]=0.f; o_acc[dt][2]=0.f; o_acc[dt][3]=0.f; }
    o_l[0]=0.f; o_l[1]=0.f; o_l[2]=0.f; o_l[3]=0.f;

    auto STAGE = [&](int buf, int ck) {
        const int mc0 = ck * 64;
        __hip_bfloat16* kb = k_ls + buf*4096;
        __hip_bfloat16* vb = v_ls + buf*4096;
        #pragma unroll
        for (int p = 0; p < 2; p++) {
            int idx = t + p*256;
            int row = idx >> 3, sl = idx & 7;
            int sk = sl ^ (row & 7);
            gload16(KTg + (size_t)(mc0+row)*64 + sk*8, kb + idx*8);
            gload16(Vg + (size_t)row*NN + mc0 + sk*8, vb + idx*8);
        }
    };

    STAGE(0, 0);
    __syncthreads();
    int cur = 0;

    for (int ck = 0; ck < 16; ck++) {
        if (ck < 15) STAGE(cur ^ 1, ck + 1);

        const __hip_bfloat16* kb = k_ls + cur*4096;
        const __hip_bfloat16* vb = v_ls + cur*4096;

        // QK^T (S^T): A=K-frag rows=keys, B=Q-frag cols=queries (already log2-scaled)
        f32x4 s_acc[4];
        __builtin_amdgcn_s_setprio(1);
        #pragma unroll
        for (int mt = 0; mt < 4; mt++) {
            f32x4 c; c[0]=0.f; c[1]=0.f; c[2]=0.f; c[3]=0.f;
            #pragma unroll
            for (int hf = 0; hf < 2; hf++) {
                int row = mt*16 + li;
                int sl = ((hf<<2) + g) ^ (li & 7);
                bf16x8 kf = *(const bf16x8*)(kb + row*64 + sl*8);
                c = MFMA16(kf, qf[hf], c);
            }
            s_acc[mt] = c;
        }
        __builtin_amdgcn_s_setprio(0);

        // row max over the lane's 16 scores (max3-friendly tree), then cross-lane
        float tm0 = fmaxf(fmaxf(s_acc[0][0], s_acc[0][1]), fmaxf(s_acc[0][2], s_acc[0][3]));
        float tm1 = fmaxf(fmaxf(s_acc[1][0], s_acc[1][1]), fmaxf(s_acc[1][2], s_acc[1][3]));
        float tm2 = fmaxf(fmaxf(s_acc[2][0], s_acc[2][1]), fmaxf(s_acc[2][2], s_acc[2][3]));
        float tm3 = fmaxf(fmaxf(s_acc[3][0], s_acc[3][1]), fmaxf(s_acc[3][2], s_acc[3][3]));
        float cmax = fmaxf(fmaxf(tm0, tm1), fmaxf(tm2, tm3));
        cmax = fmaxf(cmax, __shfl_xor(cmax, 16));
        cmax = fmaxf(cmax, __shfl_xor(cmax, 32));
        if (!__all(cmax <= m_run + 8.0f)) {       // defer-max (T13), THR=8 in log2
            float m_new = fmaxf(m_run, cmax);
            float resc = __builtin_amdgcn_exp2f(m_run - m_new);
            f32x4 rv;
            #pragma unroll
            for (int r = 0; r < 4; r++) rv[r] = __shfl(resc, 4*g + r);
            #pragma unroll
            for (int dt = 0; dt < 4; dt++) {
                o_acc[dt][0]*=rv[0]; o_acc[dt][1]*=rv[1]; o_acc[dt][2]*=rv[2]; o_acc[dt][3]*=rv[3];
            }
            o_l[0]*=rv[0]; o_l[1]*=rv[1]; o_l[2]*=rv[2]; o_l[3]*=rv[3];
            m_run = m_new;
        }

        // P = exp2(S - m), packed straight to bf16 pairs via v_cvt_pk_bf16_f32.
        // pf[ks][j] corresponds to p[8*ks + j], p[i] = exp2(s_acc[i>>2][i&3] - m_run)
        bf16x8 pf[2];
        #pragma unroll
        for (int ks = 0; ks < 2; ks++) {
            union { bf16x8 v; unsigned u[4]; } pk;
            #pragma unroll
            for (int d4 = 0; d4 < 4; d4++) {
                const int i0 = 8*ks + 2*d4, i1 = i0 + 1;
                float e0 = __builtin_amdgcn_exp2f(s_acc[i0>>2][i0&3] - m_run);
                float e1 = __builtin_amdgcn_exp2f(s_acc[i1>>2][i1&3] - m_run);
                pk.u[d4] = cvt_pk_bf16(e0, e1);
            }
            pf[ks] = pk.v;
        }

        // PV + l row-sum: A=P rows=queries; B=V-frag cols=d' / all-ones
        __builtin_amdgcn_s_setprio(1);
        #pragma unroll
        for (int dt = 0; dt < 4; dt++) {
            #pragma unroll
            for (int ks = 0; ks < 2; ks++) {
                int row = dt*16 + li;
                int sl = ((ks<<2) + g) ^ (li & 7);
                bf16x8 vf = *(const bf16x8*)(vb + row*64 + sl*8);
                o_acc[dt] = MFMA16(pf[ks], vf, o_acc[dt]);
            }
        }
        o_l = MFMA16(pf[0], onesf, o_l);
        o_l = MFMA16(pf[1], onesf, o_l);
        __builtin_amdgcn_s_setprio(0);

        __syncthreads();   // staged data ready + everyone done reading cur
        cur ^= 1;
    }

    // epilogue: out = o_acc / o_l (row r = query nq0+4g+r, lane-local l)
    f32x4 lv;
    #pragma unroll
    for (int r = 0; r < 4; r++) lv[r] = 1.0f / o_l[r];
    const int bI = bh >> 3, hI = bh & 7;
    __hip_bfloat16* vt = valsT + (size_t)bI*1024*512 + hI*64;
    #pragma unroll
    for (int dt = 0; dt < 4; dt++)
        #pragma unroll
        for (int r = 0; r < 4; r++)
            vt[(size_t)(nq0 + 4*g + r)*512 + dt*16 + li] = __float2bfloat16(o_acc[dt][r]*lv[r]);
}

extern "C" void kernel_launch(void* const* d_in, const int* in_sizes, int n_in,
                              void* d_out, int out_size, void* d_ws, size_t ws_size,
                              hipStream_t stream) {
    const float* x      = (const float*)d_in[0];
    const float* gamma  = (const float*)d_in[1];
    const float* beta   = (const float*)d_in[2];
    const float* w_qkv  = (const float*)d_in[3];
    const float* b_qkv  = (const float*)d_in[4];
    const float* w_proj = (const float*)d_in[5];
    const float* b_proj = (const float*)d_in[6];
    float* ws   = (float*)d_ws;
    float* out  = (float*)d_out;
    __hip_bfloat16* xnT   = (__hip_bfloat16*)(ws + WS_XNT);
    __hip_bfloat16* QT    = (__hip_bfloat16*)(ws + WS_QT);
    __hip_bfloat16* KT    = (__hip_bfloat16*)(ws + WS_KT);
    __hip_bfloat16* Vx    = (__hip_bfloat16*)(ws + WS_V);
    __hip_bfloat16* valsT = (__hip_bfloat16*)(ws + WS_VALST);
    __hip_bfloat16* wqb   = (__hip_bfloat16*)(ws + WS_WQB);
    __hip_bfloat16* wpb   = (__hip_bfloat16*)(ws + WS_WPB);

    to_bf16_both<<<dim3(1024), dim3(256), 0, stream>>>(w_qkv, wqb, w_proj, wpb);
    reduce_partial<<<dim3(NB*64), dim3(256), 0, stream>>>(x, ws);
    finalize_stats<<<dim3(1), dim3(64), 0, stream>>>(ws);
    normalize_t<<<dim3(1024), dim3(256), 0, stream>>>(x, gamma, beta, ws, xnT);
    gemm_mfma<12, 1><<<dim3(768), dim3(256), 0, stream>>>(wqb, xnT, b_qkv,
                                                          nullptr, QT, KT, Vx);
    attn_mfma<<<dim3(1024), dim3(256), 0, stream>>>(QT, KT, Vx, valsT);
    gemm_mfma<4, 0><<<dim3(256), dim3(256), 0, stream>>>(wpb, valsT, b_proj,
                                                         out, nullptr, nullptr, nullptr);
}

// Round 8
// 81.688 us; speedup vs baseline: 9.2066x; 1.0629x over previous
//
#include <hip/hip_runtime.h>
#include <hip/hip_bf16.h>
#include <math.h>

#define NB 8
#define NC 512
#define NN 1024      // H*W
#define NHEADS 8
#define EPSV 1e-5f
#define SC2F 0.06376351307f   // 512^-0.5 * log2(e)

typedef __attribute__((ext_vector_type(8))) short bf16x8;
typedef __attribute__((ext_vector_type(4))) short bf16x4;
typedef __attribute__((ext_vector_type(4))) float f32x4;
typedef __attribute__((ext_vector_type(16))) float f32x16;

#define MFMA16(a,b,c) __builtin_amdgcn_mfma_f32_16x16x32_bf16(a,b,c,0,0,0)
#define MFMA32(a,b,c) __builtin_amdgcn_mfma_f32_32x32x16_bf16(a,b,c,0,0,0)

static __device__ __forceinline__ short f2bf(float f) {
    __hip_bfloat16 h = __float2bfloat16(f);
    return *reinterpret_cast<short*>(&h);
}

static __device__ __forceinline__ unsigned cvt_pk_bf16(float lo, float hi) {
    unsigned r;
    asm("v_cvt_pk_bf16_f32 %0, %1, %2" : "=v"(r) : "v"(lo), "v"(hi));
    return r;
}

static __device__ __forceinline__ void gload16(const void* g, void* l) {
    __builtin_amdgcn_global_load_lds((const __attribute__((address_space(1))) void*)g,
                                     (__attribute__((address_space(3))) void*)l, 16, 0, 0);
}

// ws layout (float offsets):
#define WS_PART_SUM 0            // 512
#define WS_PART_SQ  1024         // 512
#define WS_XNT   4096                    // bf16 [8][1024][512]
#define WS_QT    (WS_XNT  + 2097152)     // bf16 [64][1024][64]  (d fragment-permuted, pre-scaled)
#define WS_KT    (WS_QT   + 2097152)     // bf16 [64][1024][64]  (d fragment-permuted)
#define WS_V     (WS_KT   + 2097152)     // bf16 [64][64][1024]  (keys permuted within 64-groups)
#define WS_VALST (WS_V    + 2097152)     // bf16 [8][1024][512]
#define WS_WQB   (WS_VALST+ 2097152)     // bf16 [1536][512]
#define WS_WPB   (WS_WQB  + 393216)      // bf16 [512][512]

// ---------------- prep: batch-stat partials (blocks 0-511) + weight convert (512-1535) ----------------
__global__ __launch_bounds__(256) void prep_kernel(const float* __restrict__ x,
                                                   const float* __restrict__ wq,
                                                   const float* __restrict__ wp,
                                                   float* __restrict__ ws) {
    int blk = blockIdx.x;
    if (blk < 512) {
        // partial sum/sumsq per batch
        int b = blk >> 6;
        int s = blk & 63;
        const float* xb = x + (size_t)b * (NC * NN) + (size_t)s * 8192;
        float sum = 0.f, sq = 0.f;
        for (int i = threadIdx.x; i < 2048; i += 256) {
            float4 v = ((const float4*)xb)[i];
            sum += v.x + v.y + v.z + v.w;
            sq  += v.x*v.x + v.y*v.y + v.z*v.z + v.w*v.w;
        }
        #pragma unroll
        for (int off = 32; off; off >>= 1) {
            sum += __shfl_down(sum, off);
            sq  += __shfl_down(sq,  off);
        }
        __shared__ float s1[4], s2[4];
        int wave = threadIdx.x >> 6, lane = threadIdx.x & 63;
        if (lane == 0) { s1[wave] = sum; s2[wave] = sq; }
        __syncthreads();
        if (threadIdx.x == 0) {
            float a = 0.f, c2 = 0.f;
            #pragma unroll
            for (int w = 0; w < 4; w++) { a += s1[w]; c2 += s2[w]; }
            ws[WS_PART_SUM + b*64 + s] = a;
            ws[WS_PART_SQ  + b*64 + s] = c2;
        }
    } else {
        // fp32 -> bf16 weight convert
        int i = (blk - 512) * 256 + threadIdx.x;   // 0..262143
        const float* s;
        __hip_bfloat16* d;
        if (i < 196608) { s = wq; d = (__hip_bfloat16*)(ws + WS_WQB); }
        else            { s = wp; d = (__hip_bfloat16*)(ws + WS_WPB); i -= 196608; }
        float4 v = ((const float4*)s)[i];
        bf16x4 w;
        w[0] = f2bf(v.x); w[1] = f2bf(v.y); w[2] = f2bf(v.z); w[3] = f2bf(v.w);
        *(bf16x4*)(d + (size_t)i*4) = w;
    }
}

// ---------------- normalize + transpose -> xnT[b][n][c] bf16 (stats finalized inline) ----------------
__global__ __launch_bounds__(256) void normalize_t(const float* __restrict__ x,
                                                   const float* __restrict__ gamma,
                                                   const float* __restrict__ beta,
                                                   const float* __restrict__ ws,
                                                   __hip_bfloat16* __restrict__ xnT) {
    int nt = blockIdx.x & 15, ct = (blockIdx.x >> 4) & 7, b = blockIdx.x >> 7;
    __shared__ __hip_bfloat16 tb[64][72];
    // redundant per-thread finalize of batch stats (64 partials, L2-hit)
    float s = 0.f, q = 0.f;
    const float4* ps = (const float4*)(ws + WS_PART_SUM + b*64);
    const float4* pq = (const float4*)(ws + WS_PART_SQ  + b*64);
    #pragma unroll
    for (int i = 0; i < 16; i++) {
        float4 a = ps[i]; s += a.x + a.y + a.z + a.w;
        float4 c = pq[i]; q += c.x + c.y + c.z + c.w;
    }
    const float inv = 1.f / (float)(NC * NN);
    float mu   = s * inv;
    float var  = q * inv - mu * mu;
    float rstd = rsqrtf(var + EPSV);

    const float* xb = x + ((size_t)b*512 + ct*64)*1024 + nt*64;
    int t = threadIdx.x;
    int cl = t >> 4, n4 = (t & 15) * 4;
    #pragma unroll
    for (int i = 0; i < 4; i++) {
        int c = i*16 + cl;
        float gm = gamma[ct*64 + c];
        float g = gm * rstd;
        float be = beta[ct*64 + c] - mu * g;
        float4 v = *(const float4*)(xb + (size_t)c*1024 + n4);
        tb[n4+0][c] = __float2bfloat16(v.x*g + be);
        tb[n4+1][c] = __float2bfloat16(v.y*g + be);
        tb[n4+2][c] = __float2bfloat16(v.z*g + be);
        tb[n4+3][c] = __float2bfloat16(v.w*g + be);
    }
    __syncthreads();
    #pragma unroll
    for (int i = 0; i < 2; i++) {
        int idx = i*256 + t;
        int n = idx >> 3, c8 = (idx & 7) * 8;
        *(bf16x8*)(xnT + ((size_t)b*1024 + nt*64 + n)*512 + ct*64 + c8) =
            *(const bf16x8*)&tb[n][c8];
    }
}

// ---------------- MFMA bf16 GEMM: Y[o][n] = sum_c A[o][c] * BxT[n][c] ----------------
template<int OT, int MODE>
__global__ __launch_bounds__(256) void gemm_mfma(const __hip_bfloat16* __restrict__ Aw,
                                                 const __hip_bfloat16* __restrict__ Bx,
                                                 const float* __restrict__ bias,
                                                 float* __restrict__ Yout,
                                                 __hip_bfloat16* __restrict__ QTx,
                                                 __hip_bfloat16* __restrict__ KTx,
                                                 __hip_bfloat16* __restrict__ Vx) {
    __shared__ __align__(16) __hip_bfloat16 lds_raw[17408];
    // batch-affinity XCD swizzle: all blocks of batch bb land on XCD bb
    const int bx = blockIdx.x;
    const int swz = (bx & 7) * (OT * 8) + (bx >> 3);
    const int nt = swz & 7;
    const int ot = (swz >> 3) % OT;
    const int bb = swz / (8 * OT);
    const int o0 = ot * 128, n0 = nt * 128;

    const int t = threadIdx.x, wv = t >> 6, l = t & 63;
    const int lr = l & 31, lh = l >> 5;
    const int wr = wv >> 1, wc = wv & 1;

    const __hip_bfloat16* Ag = Aw + (size_t)o0 * 512;
    const __hip_bfloat16* Bg = Bx + ((size_t)bb * 1024 + n0) * 512;
    __hip_bfloat16* Ab = lds_raw;
    __hip_bfloat16* Bb = lds_raw + 128*64;

    f32x16 acc[2][2];
    #pragma unroll
    for (int a1 = 0; a1 < 2; a1++)
        #pragma unroll
        for (int a2 = 0; a2 < 2; a2++)
            #pragma unroll
            for (int r = 0; r < 16; r++) acc[a1][a2][r] = 0.f;

    const int srow = wv*8 + (l >> 3);
    const int sblk = (l & 7) ^ (l >> 3);

    for (int k0 = 0; k0 < 512; k0 += 64) {
        __syncthreads();
        #pragma unroll
        for (int c = 0; c < 4; c++) {
            int row = c*32 + srow;
            gload16(Ag + (size_t)row*512 + k0 + sblk*8, Ab + (c*32 + wv*8)*64);
            gload16(Bg + (size_t)row*512 + k0 + sblk*8, Bb + (c*32 + wv*8)*64);
        }
        __syncthreads();
        #pragma unroll
        for (int ks = 0; ks < 4; ks++) {
            bf16x8 af[2], bfr[2];
            #pragma unroll
            for (int mi = 0; mi < 2; mi++) {
                int row = wr*64 + mi*32 + lr;
                af[mi] = *(const bf16x8*)(Ab + row*64 + (((ks*2 + lh) ^ (row & 7)) * 8));
            }
            #pragma unroll
            for (int ni = 0; ni < 2; ni++) {
                int row = wc*64 + ni*32 + lr;
                bfr[ni] = *(const bf16x8*)(Bb + row*64 + (((ks*2 + lh) ^ (row & 7)) * 8));
            }
            acc[0][0] = MFMA32(af[0], bfr[0], acc[0][0]);
            acc[0][1] = MFMA32(af[0], bfr[1], acc[0][1]);
            acc[1][0] = MFMA32(af[1], bfr[0], acc[1][0]);
            acc[1][1] = MFMA32(af[1], bfr[1], acc[1][1]);
        }
    }

    // C/D map (verified m74/m101): col = lr, row = (r&3) + 8*(r>>2) + 4*lh
    if (MODE == 0) {
        #pragma unroll
        for (int mi = 0; mi < 2; mi++)
            #pragma unroll
            for (int q = 0; q < 4; q++) {
                int obase = o0 + wr*64 + mi*32 + 8*q + 4*lh;
                float4 bv = *(const float4*)(bias + obase);
                #pragma unroll
                for (int ni = 0; ni < 2; ni++) {
                    int nn = n0 + wc*64 + ni*32 + lr;
                    #pragma unroll
                    for (int j = 0; j < 4; j++)
                        Yout[((size_t)bb*512 + obase + j)*1024 + nn] = acc[mi][ni][q*4+j] + bv[j];
                }
            }
    } else {
        int sec = o0 >> 9;                 // 0=Q 1=K 2=V
        if (sec == 2) {
            int od0 = o0 & 511;
            // permute keys within 64-groups: m=32ks+16u+4g+j -> p=32ks+8g+4u+j
            int mperm = ((lr & 12) << 1) + ((lr & 16) >> 2) + (lr & 3);
            #pragma unroll
            for (int mi = 0; mi < 2; mi++)
                #pragma unroll
                for (int q = 0; q < 4; q++) {
                    int ob = wr*64 + mi*32 + 8*q + 4*lh;
                    float4 bv = *(const float4*)(bias + o0 + ob);
                    #pragma unroll
                    for (int j = 0; j < 4; j++) {
                        int ol = od0 + ob + j;
                        int h = ol >> 6, d = ol & 63;
                        __hip_bfloat16* dst = Vx + ((size_t)((bb<<3) + h)*64 + d)*1024;
                        #pragma unroll
                        for (int ni = 0; ni < 2; ni++) {
                            int nn = n0 + wc*64 + ni*32 + mperm;
                            dst[nn] = __float2bfloat16(acc[mi][ni][q*4+j] + bv[j]);
                        }
                    }
                }
        } else {
            // Q gets pre-scaled by 512^-0.5*log2(e) so attention skips the scale mul
            const float qs = (sec == 0) ? SC2F : 1.0f;
            __syncthreads();
            __hip_bfloat16* tb = lds_raw;  // [128][136]
            #pragma unroll
            for (int mi = 0; mi < 2; mi++)
                #pragma unroll
                for (int q = 0; q < 4; q++) {
                    int ob = wr*64 + mi*32 + 8*q + 4*lh;
                    float4 bv = *(const float4*)(bias + o0 + ob);
                    #pragma unroll
                    for (int ni = 0; ni < 2; ni++) {
                        int nn = wc*64 + ni*32 + lr;
                        bf16x4 w;
                        #pragma unroll
                        for (int j = 0; j < 4; j++) w[j] = f2bf((acc[mi][ni][q*4+j] + bv[j]) * qs);
                        *(bf16x4*)&tb[(size_t)nn*136 + ob] = w;
                    }
                }
            __syncthreads();
            __hip_bfloat16* dst0 = (sec == 0) ? QTx : KTx;
            int h0 = (o0 & 511) >> 6;
            // d-permuted store: position-group slot holds logical d {32hf+4g+j, 32hf+16+4g+j}
            #pragma unroll
            for (int i = 0; i < 8; i++) {
                int idx = i*256 + t;
                int n = idx >> 4, rem = idx & 15;
                int hh = rem >> 3, slot = rem & 7;
                int hf32 = (slot & 4) << 3;
                int g4   = (slot & 3) << 2;
                bf16x4 lo = *(const bf16x4*)&tb[(size_t)n*136 + hh*64 + hf32 + g4];
                bf16x4 hi = *(const bf16x4*)&tb[(size_t)n*136 + hh*64 + hf32 + 16 + g4];
                bf16x8 w;
                w[0]=lo[0]; w[1]=lo[1]; w[2]=lo[2]; w[3]=lo[3];
                w[4]=hi[0]; w[5]=hi[1]; w[6]=hi[2]; w[7]=hi[3];
                *(bf16x8*)(dst0 + ((size_t)((bb<<3) + h0 + hh)*1024 + n0 + n)*64 + slot*8) = w;
            }
        }
    }
}

// ---------------- MFMA flash attention, defer-max softmax (round-6 verified numerics) ----------------
__global__ __launch_bounds__(256) void attn_mfma(const __hip_bfloat16* __restrict__ QT,
                                                 const __hip_bfloat16* __restrict__ KT,
                                                 const __hip_bfloat16* __restrict__ Vb,
                                                 __hip_bfloat16* __restrict__ valsT) {
    // XCD-grouped decomposition: all 16 q-tiles of one (b,h) share an XCD
    const int bh = ((blockIdx.x & 7) << 3) | ((blockIdx.x >> 3) & 7);
    const int qt = blockIdx.x >> 6;
    const int t = threadIdx.x;
    const int wv = t >> 6, lane = t & 63;
    const int g = lane >> 4, li = lane & 15;

    const __hip_bfloat16* QTg = QT + (size_t)bh * NN * 64;
    const __hip_bfloat16* KTg = KT + (size_t)bh * NN * 64;
    const __hip_bfloat16* Vg  = Vb + (size_t)bh * 64 * NN;

    __shared__ __align__(16) __hip_bfloat16 k_ls[2*4096];
    __shared__ __align__(16) __hip_bfloat16 v_ls[2*4096];

    const int nq0 = qt*64 + wv*16;

    // Q fragments: pre-scaled + fragment-permuted in global
    bf16x8 qf[2];
    {
        const __hip_bfloat16* qp = QTg + (size_t)(nq0 + li) * 64;
        qf[0] = *(const bf16x8*)(qp + 8*g);
        qf[1] = *(const bf16x8*)(qp + 32 + 8*g);
    }

    // all-ones B fragment (bf16 1.0) for the l row-sum MFMA
    bf16x8 onesf;
    #pragma unroll
    for (int j = 0; j < 8; j++) onesf[j] = (short)0x3F80;

    float m_run = -1e30f;
    f32x4 o_acc[4], o_l;
    #pragma unroll
    for (int dt = 0; dt < 4; dt++) { o_acc[dt][0]=0.f; o_acc[dt][1]=0.f; o_acc[dt][2]=0.f; o_acc[dt][3]=0.f; }
    o_l[0]=0.f; o_l[1]=0.f; o_l[2]=0.f; o_l[3]=0.f;

    auto STAGE = [&](int buf, int ck) {
        const int mc0 = ck * 64;
        __hip_bfloat16* kb = k_ls + buf*4096;
        __hip_bfloat16* vb = v_ls + buf*4096;
        #pragma unroll
        for (int p = 0; p < 2; p++) {
            int idx = t + p*256;
            int row = idx >> 3, sl = idx & 7;
            int sk = sl ^ (row & 7);
            gload16(KTg + (size_t)(mc0+row)*64 + sk*8, kb + idx*8);
            gload16(Vg + (size_t)row*NN + mc0 + sk*8, vb + idx*8);
        }
    };

    STAGE(0, 0);
    __syncthreads();
    int cur = 0;

    for (int ck = 0; ck < 16; ck++) {
        if (ck < 15) STAGE(cur ^ 1, ck + 1);

        const __hip_bfloat16* kb = k_ls + cur*4096;
        const __hip_bfloat16* vb = v_ls + cur*4096;

        // QK^T (S^T): A=K-frag rows=keys, B=Q-frag cols=queries (already log2-scaled)
        f32x4 s_acc[4];
        __builtin_amdgcn_s_setprio(1);
        #pragma unroll
        for (int mt = 0; mt < 4; mt++) {
            f32x4 c; c[0]=0.f; c[1]=0.f; c[2]=0.f; c[3]=0.f;
            #pragma unroll
            for (int hf = 0; hf < 2; hf++) {
                int row = mt*16 + li;
                int sl = ((hf<<2) + g) ^ (li & 7);
                bf16x8 kf = *(const bf16x8*)(kb + row*64 + sl*8);
                c = MFMA16(kf, qf[hf], c);
            }
            s_acc[mt] = c;
        }
        __builtin_amdgcn_s_setprio(0);

        // row max via v_max3-fusable chain (exact, 8 instrs), then cross-lane
        float cmax = fmaxf(s_acc[0][0], s_acc[0][1]);
        cmax = fmaxf(fmaxf(cmax, s_acc[0][2]), s_acc[0][3]);
        cmax = fmaxf(fmaxf(cmax, s_acc[1][0]), s_acc[1][1]);
        cmax = fmaxf(fmaxf(cmax, s_acc[1][2]), s_acc[1][3]);
        cmax = fmaxf(fmaxf(cmax, s_acc[2][0]), s_acc[2][1]);
        cmax = fmaxf(fmaxf(cmax, s_acc[2][2]), s_acc[2][3]);
        cmax = fmaxf(fmaxf(cmax, s_acc[3][0]), s_acc[3][1]);
        cmax = fmaxf(fmaxf(cmax, s_acc[3][2]), s_acc[3][3]);
        cmax = fmaxf(cmax, __shfl_xor(cmax, 16));
        cmax = fmaxf(cmax, __shfl_xor(cmax, 32));
        if (!__all(cmax <= m_run + 8.0f)) {       // defer-max (T13), THR=8 in log2
            float m_new = fmaxf(m_run, cmax);
            float resc = __builtin_amdgcn_exp2f(m_run - m_new);
            f32x4 rv;
            #pragma unroll
            for (int r = 0; r < 4; r++) rv[r] = __shfl(resc, 4*g + r);
            #pragma unroll
            for (int dt = 0; dt < 4; dt++) {
                o_acc[dt][0]*=rv[0]; o_acc[dt][1]*=rv[1]; o_acc[dt][2]*=rv[2]; o_acc[dt][3]*=rv[3];
            }
            o_l[0]*=rv[0]; o_l[1]*=rv[1]; o_l[2]*=rv[2]; o_l[3]*=rv[3];
            m_run = m_new;
        }

        // P = exp2(S - m), packed straight to bf16 pairs via v_cvt_pk_bf16_f32.
        // pf[ks][j] corresponds to p[8*ks + j], p[i] = exp2(s_acc[i>>2][i&3] - m_run)
        bf16x8 pf[2];
        #pragma unroll
        for (int ks = 0; ks < 2; ks++) {
            union { bf16x8 v; unsigned u[4]; } pk;
            #pragma unroll
            for (int d4 = 0; d4 < 4; d4++) {
                const int i0 = 8*ks + 2*d4, i1 = i0 + 1;
                float e0 = __builtin_amdgcn_exp2f(s_acc[i0>>2][i0&3] - m_run);
                float e1 = __builtin_amdgcn_exp2f(s_acc[i1>>2][i1&3] - m_run);
                pk.u[d4] = cvt_pk_bf16(e0, e1);
            }
            pf[ks] = pk.v;
        }

        // PV + l row-sum: A=P rows=queries; B=V-frag cols=d' / all-ones
        __builtin_amdgcn_s_setprio(1);
        #pragma unroll
        for (int dt = 0; dt < 4; dt++) {
            #pragma unroll
            for (int ks = 0; ks < 2; ks++) {
                int row = dt*16 + li;
                int sl = ((ks<<2) + g) ^ (li & 7);
                bf16x8 vf = *(const bf16x8*)(vb + row*64 + sl*8);
                o_acc[dt] = MFMA16(pf[ks], vf, o_acc[dt]);
            }
        }
        o_l = MFMA16(pf[0], onesf, o_l);
        o_l = MFMA16(pf[1], onesf, o_l);
        __builtin_amdgcn_s_setprio(0);

        __syncthreads();   // staged data ready + everyone done reading cur
        cur ^= 1;
    }

    // epilogue: out = o_acc / o_l (row r = query nq0+4g+r, lane-local l)
    f32x4 lv;
    #pragma unroll
    for (int r = 0; r < 4; r++) lv[r] = 1.0f / o_l[r];
    const int bI = bh >> 3, hI = bh & 7;
    __hip_bfloat16* vt = valsT + (size_t)bI*1024*512 + hI*64;
    #pragma unroll
    for (int dt = 0; dt < 4; dt++)
        #pragma unroll
        for (int r = 0; r < 4; r++)
            vt[(size_t)(nq0 + 4*g + r)*512 + dt*16 + li] = __float2bfloat16(o_acc[dt][r]*lv[r]);
}

extern "C" void kernel_launch(void* const* d_in, const int* in_sizes, int n_in,
                              void* d_out, int out_size, void* d_ws, size_t ws_size,
                              hipStream_t stream) {
    const float* x      = (const float*)d_in[0];
    const float* gamma  = (const float*)d_in[1];
    const float* beta   = (const float*)d_in[2];
    const float* w_qkv  = (const float*)d_in[3];
    const float* b_qkv  = (const float*)d_in[4];
    const float* w_proj = (const float*)d_in[5];
    const float* b_proj = (const float*)d_in[6];
    float* ws   = (float*)d_ws;
    float* out  = (float*)d_out;
    __hip_bfloat16* xnT   = (__hip_bfloat16*)(ws + WS_XNT);
    __hip_bfloat16* QT    = (__hip_bfloat16*)(ws + WS_QT);
    __hip_bfloat16* KT    = (__hip_bfloat16*)(ws + WS_KT);
    __hip_bfloat16* Vx    = (__hip_bfloat16*)(ws + WS_V);
    __hip_bfloat16* valsT = (__hip_bfloat16*)(ws + WS_VALST);
    __hip_bfloat16* wqb   = (__hip_bfloat16*)(ws + WS_WQB);
    __hip_bfloat16* wpb   = (__hip_bfloat16*)(ws + WS_WPB);

    prep_kernel<<<dim3(1536), dim3(256), 0, stream>>>(x, w_qkv, w_proj, ws);
    normalize_t<<<dim3(1024), dim3(256), 0, stream>>>(x, gamma, beta, ws, xnT);
    gemm_mfma<12, 1><<<dim3(768), dim3(256), 0, stream>>>(wqb, xnT, b_qkv,
                                                          nullptr, QT, KT, Vx);
    attn_mfma<<<dim3(1024), dim3(256), 0, stream>>>(QT, KT, Vx, valsT);
    gemm_mfma<4, 0><<<dim3(256), dim3(256), 0, stream>>>(wpb, valsT, b_proj,
                                                         out, nullptr, nullptr, nullptr);
}